// Round 16
// baseline (464.808 us; speedup 1.0000x reference)
//
#include <hip/hip_runtime.h>
#include <stdint.h>

#define NEGF (-1e30f)

typedef unsigned short ushort_t;
typedef unsigned char uchar_t;
typedef __attribute__((ext_vector_type(2))) long v2i64;
typedef __attribute__((ext_vector_type(4))) float f32x4;
typedef __attribute__((ext_vector_type(8))) int v8i32_t;

constexpr int cB = 4, cT = 256, cU = 64, cU1 = 65, cV = 1024, cF = 80, cH = 512, cJ = 512;
constexpr int cM = cB * cT * cU1; // 66560
constexpr int cTU = cT * cU1;     // 16640 (per-batch (u,t) plane: u*256+t)

// Padé(2,2) tanh + clamp: max err ~0.016, far below fp8-e4m3 half-step; no v_exp.
__device__ __forceinline__ float tanh_fast(float x){
  float t = x * x;
  float num = x * (27.f + t);
  float den = fmaf(9.f, t, 27.f);
  float r = num * __builtin_amdgcn_rcpf(den);
  return fminf(1.f, fmaxf(-1.f, r));
}

__device__ __forceinline__ float logadd(float x, float y){
  float m = fmaxf(x, y);
  return m + __logf(1.f + __expf(-fabsf(x - y)));
}

__device__ __forceinline__ int pk8(float a, float b, float c, float d){
  int v = __builtin_amdgcn_cvt_pk_fp8_f32(a, b, 0, false);
  v = __builtin_amdgcn_cvt_pk_fp8_f32(c, d, v, true);
  return v;
}

// ------------- fused prologue: 3 independent jobs in one dispatch -------------
// bid 0..39   : Wcomb(80,512)  = W_enc @ W_jenc
// bid 40..169 : dmatb(260,512) = emb[padded] @ W_jdec + b_j
// bid 170..185: WTf8 fp8 fragment-order transpose of 32*W_out (MX K=128 frags, 32B/lane)
__global__ __launch_bounds__(256) void k_pre(
    const float* __restrict__ W_enc, const float* __restrict__ W_jenc,
    float* __restrict__ Wcomb,
    const float* __restrict__ emb, const int* __restrict__ targets,
    const float* __restrict__ W_jdec, const float* __restrict__ b_j,
    float* __restrict__ dmatb,
    const float* __restrict__ W_out, uchar_t* __restrict__ WTf8)
{
  __shared__ float sA[4][512];
  int bid = blockIdx.x;
  int tid = threadIdx.x;

  if (bid < 170){
    bool isW = (bid < 40);
    int id = isW ? bid : bid - 40;
    int bx = id & 1, by = id >> 1;
    int m0 = by * 4;
    int col = bx * 256 + tid;
    const float* Bm = isW ? W_jenc : W_jdec;
    for (int i = tid; i < 4 * 512; i += 256){
      int r = i >> 9, c = i & 511;
      if (isW){
        sA[r][c] = W_enc[(size_t)(m0 + r) * 512 + c];
      } else {
        int row = m0 + r;
        int b = row / cU1, u = row % cU1;
        int src = (u == 0) ? 0 : targets[b * cU + (u - 1)];
        sA[r][c] = emb[(size_t)src * cH + c];
      }
    }
    __syncthreads();
    float a0 = 0.f, a1 = 0.f, a2 = 0.f, a3 = 0.f;
#pragma unroll 8
    for (int k = 0; k < 512; k++){
      float bv = Bm[(size_t)k * cJ + col];
      a0 = fmaf(sA[0][k], bv, a0);
      a1 = fmaf(sA[1][k], bv, a1);
      a2 = fmaf(sA[2][k], bv, a2);
      a3 = fmaf(sA[3][k], bv, a3);
    }
    float bb = isW ? 0.f : b_j[col];
    float* C = isW ? Wcomb : dmatb;
    C[(size_t)(m0 + 0) * cJ + col] = a0 + bb;
    C[(size_t)(m0 + 1) * cJ + col] = a1 + bb;
    C[(size_t)(m0 + 2) * cJ + col] = a2 + bb;
    C[(size_t)(m0 + 3) * cJ + col] = a3 + bb;
  } else {
    // WTf8[bn4][kq][nt16][lane][32]: col n = bn4*256+nt16*16+(lane&15),
    // k-bytes = kq*128 + (lane>>4)*32 + [0..32)
    int id = bid - 170;                  // 0..15
    int bn4 = id & 3, kq = id >> 2;      // kq 0..3
    int lane = tid & 63, nth = tid >> 6;
    int c16 = lane & 15, quad = lane >> 4;
    int jA = kq * 128 + quad * 32;
#pragma unroll
    for (int i = 0; i < 4; i++){
      int nt16 = nth * 4 + i;
      int n = bn4 * 256 + nt16 * 16 + c16;
      unsigned int p[8];
#pragma unroll
      for (int h = 0; h < 8; h++){
        int j0 = jA + h * 4;
        float w0 = W_out[(size_t)(j0 + 0) * cV + n] * 32.f;
        float w1 = W_out[(size_t)(j0 + 1) * cV + n] * 32.f;
        float w2 = W_out[(size_t)(j0 + 2) * cV + n] * 32.f;
        float w3 = W_out[(size_t)(j0 + 3) * cV + n] * 32.f;
        p[h] = (unsigned)pk8(w0, w1, w2, w3);
      }
      uchar_t* dst = WTf8 + (size_t)bn4 * 131072 + (((size_t)kq * 16 + nt16) * 64 + lane) * 32;
      uint4 lo; lo.x = p[0]; lo.y = p[1]; lo.z = p[2]; lo.w = p[3];
      uint4 hi; hi.x = p[4]; hi.y = p[5]; hi.z = p[6]; hi.w = p[7];
      *(uint4*)dst = lo;
      *(uint4*)(dst + 16) = hi;
    }
  }
}

// ------------- e = inputs @ Wcomb  (K=80), 4 rows/block -------------
__global__ void k_gemm_e(const float* __restrict__ A, const float* __restrict__ Bm,
                         float* __restrict__ C){
  __shared__ float sA[4][80];
  int m0 = blockIdx.y * 4;
  int col = blockIdx.x * 256 + threadIdx.x;
  for (int i = threadIdx.x; i < 4 * 80; i += 256)
    sA[i / 80][i % 80] = A[(size_t)(m0 + i / 80) * 80 + (i % 80)];
  __syncthreads();
  float a0 = 0.f, a1 = 0.f, a2 = 0.f, a3 = 0.f;
#pragma unroll 8
  for (int k = 0; k < 80; k++){
    float bv = Bm[(size_t)k * cJ + col];
    a0 = fmaf(sA[0][k], bv, a0);
    a1 = fmaf(sA[1][k], bv, a1);
    a2 = fmaf(sA[2][k], bv, a2);
    a3 = fmaf(sA[3][k], bv, a3);
  }
  C[(size_t)(m0 + 0) * cJ + col] = a0;
  C[(size_t)(m0 + 1) * cJ + col] = a1;
  C[(size_t)(m0 + 2) * cJ + col] = a2;
  C[(size_t)(m0 + 3) * cJ + col] = a3;
}

// ------------- H fp8 MX-fragment-order, t-minor, coalesced via LDS bounce -------------
// Hbf8[bm][kq][mg][lane][32]: row = mg*16+(lane&15) [local t],
// k-bytes = kq*128 + (lane>>4)*32 + [0..32)
__global__ __launch_bounds__(256) void k_hf(const float* __restrict__ e,
                                            const float* __restrict__ dmatb,
                                            uchar_t* __restrict__ Hbf8){
  __shared__ uchar_t sH[16 * 520];    // 16 rows x 512 B, pad 8 B
  int tid = threadIdx.x;
  int wid = tid >> 6, lane = tid & 63;
  int c16 = lane & 15, quad = lane >> 4;
  int bm = blockIdx.x;
  int bu = bm >> 1, thalf = bm & 1;
  int b = bu / cU1;
  int t0 = thalf * 128;

  float dj[8];
  const float4* dp = (const float4*)(dmatb + (size_t)bu * cJ + lane * 8);
  float4 dA = dp[0], dB = dp[1];
  dj[0] = dA.x; dj[1] = dA.y; dj[2] = dA.z; dj[3] = dA.w;
  dj[4] = dB.x; dj[5] = dB.y; dj[6] = dB.z; dj[7] = dB.w;

  const float* erow0 = e + ((size_t)(b * cT + t0)) * cJ + lane * 8;
  uchar_t* outb = Hbf8 + (size_t)bm * 65536 + lane * 32;

  for (int mg = 0; mg < 8; mg++){
#pragma unroll
    for (int rr = 0; rr < 4; rr++){
      int rloc = wid * 4 + rr;
      const float* ep = erow0 + ((size_t)(mg * 16 + rloc)) * cJ;
      float4 e0 = *(const float4*)ep;
      float4 e1 = *(const float4*)(ep + 4);
      int v0 = pk8(tanh_fast(e0.x + dj[0]), tanh_fast(e0.y + dj[1]),
                   tanh_fast(e0.z + dj[2]), tanh_fast(e0.w + dj[3]));
      int v1 = pk8(tanh_fast(e1.x + dj[4]), tanh_fast(e1.y + dj[5]),
                   tanh_fast(e1.z + dj[6]), tanh_fast(e1.w + dj[7]));
      uint2 pk; pk.x = (unsigned)v0; pk.y = (unsigned)v1;
      *(uint2*)(sH + rloc * 520 + lane * 8) = pk;
    }
    __syncthreads();
    // kq = wid: lane reads 32B of row c16 at byte offset wid*128 + quad*32 (8B-aligned)
    {
      const uchar_t* src = sH + c16 * 520 + wid * 128 + quad * 32;
      uint2 q0 = *(const uint2*)(src + 0);
      uint2 q1 = *(const uint2*)(src + 8);
      uint2 q2 = *(const uint2*)(src + 16);
      uint2 q3 = *(const uint2*)(src + 24);
      uchar_t* dst = outb + (((size_t)wid * 8 + mg) * 64) * 32;
      uint4 lo; lo.x = q0.x; lo.y = q0.y; lo.z = q1.x; lo.w = q1.y;
      uint4 hi; hi.x = q2.x; hi.y = q2.y; hi.z = q3.x; hi.w = q3.y;
      *(uint4*)dst = lo;
      *(uint4*)(dst + 16) = hi;
    }
    __syncthreads();
  }
}

// ------------- joint GEMM, MX-scaled fp8 K=128 (2x pipe rate), 64x64 wave tile -------------
// mfma_scale_f32_16x16x128_f8f6f4 with unit e8m0 scales (0x7F = 2^0): exact fp8 GEMM
// at the 4647 TF rate (m21/m148). 64 MFMA/wave vs 256 -> issue floor halves.
__global__ __launch_bounds__(256, 3) void k_joint(
    const uchar_t* __restrict__ Hbf8, const uchar_t* __restrict__ WTf8,
    const float* __restrict__ b_out, const int* __restrict__ targets,
    float* __restrict__ ps,                       // [8][cM]
    float* __restrict__ blank_g, float* __restrict__ lbl_g)
{
  __shared__ float redS[2][128];

  int tid = threadIdx.x;
  int wid = tid >> 6, lane = tid & 63;
  int quad = lane >> 4, c16 = lane & 15;
  int wm = wid & 1, wn = wid >> 1;
  int bid = blockIdx.x;
  int bm = ((bid >> 6) << 3) + (bid & 7);
  int bn = (bid >> 3) & 7;                       // 128-col strip
  int bu = bm >> 1, thalf = bm & 1;
  int b = bu / cU1, u = bu - b * cU1;
  int tg = (u < cU) ? targets[b * cU + u] : -1;
  int lin0 = bu * cT + thalf * 128;              // (b,u,t)-linear base

  f32x4 acc[4][4];
#pragma unroll
  for (int i = 0; i < 4; i++)
#pragma unroll
    for (int j = 0; j < 4; j++)
      acc[i][j] = (f32x4){0.f, 0.f, 0.f, 0.f};

  // A frag (kq, mg=wm*4+mt): Hbf8 + bm*65536 + ((kq*8+mg)*64+lane)*32
  const uchar_t* aP = Hbf8 + (size_t)bm * 65536 + ((size_t)(wm * 4) * 64 + lane) * 32;
  // B frag (kq, nt16=(bn&1)*8+wn*4+nt): WTf8 + bn4*131072 + ((kq*16+nt16)*64+lane)*32
  const uchar_t* bP = WTf8 + (size_t)(bn >> 1) * 131072 + ((size_t)((bn & 1) * 8 + wn * 4) * 64 + lane) * 32;

#pragma unroll
  for (int kq = 0; kq < 4; kq++){
    v8i32_t af[4], bf[4];
#pragma unroll
    for (int mt = 0; mt < 4; mt++)
      af[mt] = *(const v8i32_t*)(aP + (size_t)kq * 16384 + mt * 2048);
#pragma unroll
    for (int nt = 0; nt < 4; nt++)
      bf[nt] = *(const v8i32_t*)(bP + (size_t)kq * 32768 + nt * 2048);
#pragma unroll
    for (int mt = 0; mt < 4; mt++)
#pragma unroll
      for (int nt = 0; nt < 4; nt++)
        acc[mt][nt] = __builtin_amdgcn_mfma_scale_f32_16x16x128_f8f6f4(
            af[mt], bf[nt], acc[mt][nt], 0, 0, 0, 0x7F7F7F7F, 0, 0x7F7F7F7F);
  }

  float bv[4];
#pragma unroll
  for (int nt = 0; nt < 4; nt++) bv[nt] = b_out[bn * 128 + (wn * 4 + nt) * 16 + c16];

  bool ownL = (tg >= 0) && ((tg >> 7) == bn) && (((tg >> 6) & 1) == wn);
  int ntO = (tg >> 4) & 3;
  int tgc = tg & 15;
  const float descale = 1.f / 32.f;     // undo the *32 on W_out fp8

#pragma unroll
  for (int mt = 0; mt < 4; mt++){
#pragma unroll
    for (int r = 0; r < 4; r++){
      int rl = wm * 64 + mt * 16 + quad * 4 + r;  // C/D: col=lane&15, row=quad*4+reg (m89)
      float l[4];
#pragma unroll
      for (int nt = 0; nt < 4; nt++) l[nt] = fmaf(acc[mt][nt][r], descale, bv[nt]);
      if (bn == 0 && wn == 0 && c16 == 0) blank_g[lin0 + rl] = l[0];
      if (ownL && c16 == tgc){
        float v = l[0];
#pragma unroll
        for (int k = 1; k < 4; k++) v = (ntO == k) ? l[k] : v;
        lbl_g[lin0 + rl] = v;
      }
      float s = __expf(l[0]) + __expf(l[1]) + __expf(l[2]) + __expf(l[3]);
      s += __shfl_xor(s, 1, 64);
      s += __shfl_xor(s, 2, 64);
      s += __shfl_xor(s, 4, 64);
      s += __shfl_xor(s, 8, 64);
      if (c16 == 0) redS[wn][rl] = s;
    }
  }
  __syncthreads();
  if (tid < 128)
    ps[(size_t)bn * cM + lin0 + tid] = redS[0][tid] + redS[1][tid];
}

// ------------- parallel lse merge: 8 ps planes -> blankd/lbld -------------
__global__ __launch_bounds__(256) void k_lse(
    const float* __restrict__ ps, const float* __restrict__ blank_g,
    const float* __restrict__ lbl_g,
    float* __restrict__ blankd, float* __restrict__ lbld)
{
  int cell = blockIdx.x * 256 + threadIdx.x;   // 66560 = 260*256
  float S = 0.f;
#pragma unroll
  for (int p = 0; p < 8; p++) S += ps[(size_t)p * cM + cell];
  float lse = __logf(S);
  int u = (cell % cTU) >> 8;
  blankd[cell] = blank_g[cell] - lse;
  lbld[cell] = (u < cU) ? (lbl_g[cell] - lse) : NEGF;
}

// ------------- RNN-T alpha DP: SKIP-2 diagonal steps (r15-verified) -------------
__global__ __launch_bounds__(256) void k_dp(
    const float* __restrict__ blankd, const float* __restrict__ lbld,
    const int* __restrict__ in_len, const int* __restrict__ tgt_len,
    float* __restrict__ afin)
{
  __shared__ float sbb[cTU];   // 65 KB, (u,t): index u*256+t
  __shared__ float slb[cTU];   // 65 KB
  __shared__ float sS[256];    // alpha[t][63] history (lane 63)
  int b = blockIdx.x;
  int tl  = tgt_len[b];                // 32..64
  size_t base = (size_t)b * cTU;
  for (int i = threadIdx.x; i < cTU / 4; i += 256){
    ((float4*)sbb)[i] = ((const float4*)(blankd + base))[i];
    float4 v = ((const float4*)(lbld + base))[i];
    int row = (i * 4) >> 8;            // float4 never crosses a 256-elem row
    if (row >= tl){ v.x = NEGF; v.y = NEGF; v.z = NEGF; v.w = NEGF; }
    ((float4*)slb)[i] = v;
  }
  __syncthreads();
  if (threadIdx.x >= 64) return;

  int u = threadIdx.x;                 // 0..63
  int til = in_len[b] - 1;
  bool cap64 = (tl == 64);
  bool isTL = (u == tl);
  const float* pbu  = sbb + (u << 8);
  const float* pbu1 = sbb + (((u >= 1) ? u - 1 : 0) << 8);
  const float* plu1 = slb + (((u >= 1) ? u - 1 : 0) << 8);
  const float* plu2 = slb + (((u >= 2) ? u - 2 : 0) << 8);
  bool u1 = (u >= 1), u2 = (u >= 2);
  float fb = pbu[til];                 // blank at (u, til); used by lane tl only

  float A = (u == 0) ? 0.f : NEGF;     // alpha on even diagonal d = 2g
  float res = 0.f;

  auto ld = [&](const float* p, int i, bool ok) -> float {
    bool v = ok & (i >= 0) & (i <= 255);
    int ic = (i < 0) ? 0 : ((i > 255) ? 255 : i);
    float x = p[ic];
    return v ? x : NEGF;
  };

  int i0 = -u;
  float o0 = ld(pbu,  i0,     true);   // bb[t-2][u]
  float o1 = ld(pbu,  i0 + 1, true);   // bb[t-1][u]
  float o2 = ld(plu1, i0 + 1, u1);     // lb[t-1][u-1]
  float o3 = ld(pbu1, i0 + 1, u1);     // bb[t-1][u-1]
  float o4 = ld(plu1, i0 + 2, u1);     // lb[t][u-1]
  float o5 = ld(plu2, i0 + 2, u2);     // lb[t][u-2]

  for (int g = 0; g < 159; g++){
    float c0 = o0, c1 = o1, c2 = o2, c3 = o3, c4 = o4, c5 = o5;
    int i0n = i0 + 2;
    o0 = ld(pbu,  i0n,     true);
    o1 = ld(pbu,  i0n + 1, true);
    o2 = ld(plu1, i0n + 1, u1);
    o3 = ld(pbu1, i0n + 1, u1);
    o4 = ld(plu1, i0n + 2, u1);
    o5 = ld(plu2, i0n + 2, u2);

    float up1 = __shfl_up(A, 1, 64);
    float up2 = __shfl_up(A, 2, 64);

    float C0 = c0 + c1;
    float C1 = logadd(c2 + c1, c3 + c4);
    float C2 = c5 + c4;

    bool tv1 = (i0 + 1 >= 0) & (i0 + 1 <= 255);
    float Amid = logadd(A + c0, up1 + c2);
    Amid = tv1 ? Amid : NEGF;
    bool tv2 = (i0 + 2 >= 0) & (i0 + 2 <= 255);
    float Anew = logadd(logadd(A + C0, up1 + C1), up2 + C2);
    Anew = tv2 ? Anew : NEGF;

    if (isTL && (i0 + 1) == til) res = Amid + fb;
    if (isTL && (i0 + 2) == til) res = Anew + fb;
    if (u == 63){
      if (tv1) sS[i0 + 1] = Amid;
      if (tv2) sS[i0 + 2] = Anew;
    }
    A = Anew;
    i0 = i0n;
  }

  if (cap64){
    const float* pb64 = sbb + (64 << 8);
    const float* pl63 = slb + (63 << 8);
    float A64 = sS[0] + pl63[0];       // alpha[0][64]
    for (int t = 1; t <= til; t++)
      A64 = logadd(A64 + pb64[t - 1], sS[t] + pl63[t]);
    if (u == 0) res = A64 + pb64[til];
  }

  res += __shfl_xor(res, 1, 64);
  res += __shfl_xor(res, 2, 64);
  res += __shfl_xor(res, 4, 64);
  res += __shfl_xor(res, 8, 64);
  res += __shfl_xor(res, 16, 64);
  res += __shfl_xor(res, 32, 64);
  if (u == 0) afin[b] = res;
}

__global__ void k_final(const float* __restrict__ afin, float* __restrict__ out){
  if (threadIdx.x == 0)
    out[0] = -0.25f * (afin[0] + afin[1] + afin[2] + afin[3]);
}

extern "C" void kernel_launch(void* const* d_in, const int* in_sizes, int n_in,
                              void* d_out, int out_size, void* d_ws, size_t ws_size,
                              hipStream_t stream)
{
  (void)in_sizes; (void)n_in; (void)out_size; (void)ws_size;
  const float* inputs = (const float*)d_in[0];   // (4,256,80)
  const float* W_enc  = (const float*)d_in[1];   // (80,512)
  const float* emb    = (const float*)d_in[2];   // (1024,512)
  const float* W_jenc = (const float*)d_in[3];   // (512,512)
  const float* W_jdec = (const float*)d_in[4];   // (512,512)
  const float* b_j    = (const float*)d_in[5];   // (512)
  const float* W_out  = (const float*)d_in[6];   // (512,1024)
  const float* b_out  = (const float*)d_in[7];   // (1024)
  const int* targets  = (const int*)d_in[8];     // (4,64)
  const int* in_len   = (const int*)d_in[9];     // (4)
  const int* tgt_len  = (const int*)d_in[10];    // (4)

  char* w = (char*)d_ws;
  auto alloc = [&](size_t bytes){ char* p = w; w += (bytes + 255) & ~(size_t)255; return p; };
  float* Wcomb   = (float*)alloc((size_t)80 * 512 * 4);
  float* e       = (float*)alloc((size_t)1024 * 512 * 4);
  float* dmatb   = (float*)alloc((size_t)260 * 512 * 4);
  float* blank_g = (float*)alloc((size_t)cM * 4);
  float* lbl_g   = (float*)alloc((size_t)cM * 4);
  float* ps      = (float*)alloc((size_t)8 * cM * 4);
  float* blankd  = (float*)alloc((size_t)cM * 4);
  float* lbld    = (float*)alloc((size_t)cM * 4);
  float* afin    = (float*)alloc(256);
  uchar_t* Hbf8  = (uchar_t*)alloc((size_t)520 * 65536);
  uchar_t* WTf8  = (uchar_t*)alloc((size_t)4 * 131072);

  k_pre<<<186, 256, 0, stream>>>(W_enc, W_jenc, Wcomb, emb, targets, W_jdec, b_j, dmatb,
                                 W_out, WTf8);
  k_gemm_e<<<dim3(2, 256), 256, 0, stream>>>(inputs, Wcomb, e);
  k_hf<<<520, 256, 0, stream>>>(e, dmatb, Hbf8);
  k_joint<<<4160, 256, 0, stream>>>(Hbf8, WTf8, b_out, targets, ps, blank_g, lbl_g);
  k_lse<<<260, 256, 0, stream>>>(ps, blank_g, lbl_g, blankd, lbld);
  k_dp<<<4, 256, 0, stream>>>(blankd, lbld, in_len, tgt_len, afin);
  k_final<<<1, 64, 0, stream>>>(afin, (float*)d_out);
}

// Round 17
// 288.551 us; speedup vs baseline: 1.6108x; 1.6108x over previous
//
#include <hip/hip_runtime.h>
#include <stdint.h>

#define NEGF (-1e30f)

typedef unsigned short ushort_t;
typedef unsigned char uchar_t;
typedef __attribute__((ext_vector_type(2))) long v2i64;
typedef __attribute__((ext_vector_type(4))) float f32x4;
typedef __attribute__((ext_vector_type(8))) int v8i32_t;

constexpr int cB = 4, cT = 256, cU = 64, cU1 = 65, cV = 1024, cF = 80, cH = 512, cJ = 512;
constexpr int cM = cB * cT * cU1; // 66560
constexpr int cTU = cT * cU1;     // 16640 (per-batch (u,t) plane: u*256+t)

// Padé(2,2) tanh + clamp: max err ~0.016, far below fp8-e4m3 half-step; no v_exp.
__device__ __forceinline__ float tanh_fast(float x){
  float t = x * x;
  float num = x * (27.f + t);
  float den = fmaf(9.f, t, 27.f);
  float r = num * __builtin_amdgcn_rcpf(den);
  return fminf(1.f, fmaxf(-1.f, r));
}

__device__ __forceinline__ float logadd(float x, float y){
  float m = fmaxf(x, y);
  return m + __logf(1.f + __expf(-fabsf(x - y)));
}

__device__ __forceinline__ int pk8(float a, float b, float c, float d){
  int v = __builtin_amdgcn_cvt_pk_fp8_f32(a, b, 0, false);
  v = __builtin_amdgcn_cvt_pk_fp8_f32(c, d, v, true);
  return v;
}

// ------------- fused prologue: 3 independent jobs in one dispatch -------------
// bid 0..39   : Wcomb(80,512)  = W_enc @ W_jenc
// bid 40..169 : dmatb(260,512) = emb[padded] @ W_jdec + b_j
// bid 170..185: WTf8 fp8 fragment-order transpose of 32*W_out (MX K=128 frags, 32B/lane)
__global__ __launch_bounds__(256) void k_pre(
    const float* __restrict__ W_enc, const float* __restrict__ W_jenc,
    float* __restrict__ Wcomb,
    const float* __restrict__ emb, const int* __restrict__ targets,
    const float* __restrict__ W_jdec, const float* __restrict__ b_j,
    float* __restrict__ dmatb,
    const float* __restrict__ W_out, uchar_t* __restrict__ WTf8)
{
  __shared__ float sA[4][512];
  int bid = blockIdx.x;
  int tid = threadIdx.x;

  if (bid < 170){
    bool isW = (bid < 40);
    int id = isW ? bid : bid - 40;
    int bx = id & 1, by = id >> 1;
    int m0 = by * 4;
    int col = bx * 256 + tid;
    const float* Bm = isW ? W_jenc : W_jdec;
    for (int i = tid; i < 4 * 512; i += 256){
      int r = i >> 9, c = i & 511;
      if (isW){
        sA[r][c] = W_enc[(size_t)(m0 + r) * 512 + c];
      } else {
        int row = m0 + r;
        int b = row / cU1, u = row % cU1;
        int src = (u == 0) ? 0 : targets[b * cU + (u - 1)];
        sA[r][c] = emb[(size_t)src * cH + c];
      }
    }
    __syncthreads();
    float a0 = 0.f, a1 = 0.f, a2 = 0.f, a3 = 0.f;
#pragma unroll 8
    for (int k = 0; k < 512; k++){
      float bv = Bm[(size_t)k * cJ + col];
      a0 = fmaf(sA[0][k], bv, a0);
      a1 = fmaf(sA[1][k], bv, a1);
      a2 = fmaf(sA[2][k], bv, a2);
      a3 = fmaf(sA[3][k], bv, a3);
    }
    float bb = isW ? 0.f : b_j[col];
    float* C = isW ? Wcomb : dmatb;
    C[(size_t)(m0 + 0) * cJ + col] = a0 + bb;
    C[(size_t)(m0 + 1) * cJ + col] = a1 + bb;
    C[(size_t)(m0 + 2) * cJ + col] = a2 + bb;
    C[(size_t)(m0 + 3) * cJ + col] = a3 + bb;
  } else {
    // WTf8[bn4][kq][nt16][lane][32]: col n = bn4*256+nt16*16+(lane&15),
    // k-bytes = kq*128 + (lane>>4)*32 + [0..32)
    int id = bid - 170;                  // 0..15
    int bn4 = id & 3, kq = id >> 2;      // kq 0..3
    int lane = tid & 63, nth = tid >> 6;
    int c16 = lane & 15, quad = lane >> 4;
    int jA = kq * 128 + quad * 32;
#pragma unroll
    for (int i = 0; i < 4; i++){
      int nt16 = nth * 4 + i;
      int n = bn4 * 256 + nt16 * 16 + c16;
      unsigned int p[8];
#pragma unroll
      for (int h = 0; h < 8; h++){
        int j0 = jA + h * 4;
        float w0 = W_out[(size_t)(j0 + 0) * cV + n] * 32.f;
        float w1 = W_out[(size_t)(j0 + 1) * cV + n] * 32.f;
        float w2 = W_out[(size_t)(j0 + 2) * cV + n] * 32.f;
        float w3 = W_out[(size_t)(j0 + 3) * cV + n] * 32.f;
        p[h] = (unsigned)pk8(w0, w1, w2, w3);
      }
      uchar_t* dst = WTf8 + (size_t)bn4 * 131072 + (((size_t)kq * 16 + nt16) * 64 + lane) * 32;
      uint4 lo; lo.x = p[0]; lo.y = p[1]; lo.z = p[2]; lo.w = p[3];
      uint4 hi; hi.x = p[4]; hi.y = p[5]; hi.z = p[6]; hi.w = p[7];
      *(uint4*)dst = lo;
      *(uint4*)(dst + 16) = hi;
    }
  }
}

// ------------- e = inputs @ Wcomb  (K=80), 4 rows/block -------------
__global__ void k_gemm_e(const float* __restrict__ A, const float* __restrict__ Bm,
                         float* __restrict__ C){
  __shared__ float sA[4][80];
  int m0 = blockIdx.y * 4;
  int col = blockIdx.x * 256 + threadIdx.x;
  for (int i = threadIdx.x; i < 4 * 80; i += 256)
    sA[i / 80][i % 80] = A[(size_t)(m0 + i / 80) * 80 + (i % 80)];
  __syncthreads();
  float a0 = 0.f, a1 = 0.f, a2 = 0.f, a3 = 0.f;
#pragma unroll 8
  for (int k = 0; k < 80; k++){
    float bv = Bm[(size_t)k * cJ + col];
    a0 = fmaf(sA[0][k], bv, a0);
    a1 = fmaf(sA[1][k], bv, a1);
    a2 = fmaf(sA[2][k], bv, a2);
    a3 = fmaf(sA[3][k], bv, a3);
  }
  C[(size_t)(m0 + 0) * cJ + col] = a0;
  C[(size_t)(m0 + 1) * cJ + col] = a1;
  C[(size_t)(m0 + 2) * cJ + col] = a2;
  C[(size_t)(m0 + 3) * cJ + col] = a3;
}

// ------------- H fp8 MX-fragment-order, t-minor, coalesced via LDS bounce -------------
// Hbf8[bm][kq][mg][lane][32]: row = mg*16+(lane&15) [local t],
// k-bytes = kq*128 + (lane>>4)*32 + [0..32)
__global__ __launch_bounds__(256) void k_hf(const float* __restrict__ e,
                                            const float* __restrict__ dmatb,
                                            uchar_t* __restrict__ Hbf8){
  __shared__ uchar_t sH[16 * 520];    // 16 rows x 512 B, pad 8 B
  int tid = threadIdx.x;
  int wid = tid >> 6, lane = tid & 63;
  int c16 = lane & 15, quad = lane >> 4;
  int bm = blockIdx.x;
  int bu = bm >> 1, thalf = bm & 1;
  int b = bu / cU1;
  int t0 = thalf * 128;

  float dj[8];
  const float4* dp = (const float4*)(dmatb + (size_t)bu * cJ + lane * 8);
  float4 dA = dp[0], dB = dp[1];
  dj[0] = dA.x; dj[1] = dA.y; dj[2] = dA.z; dj[3] = dA.w;
  dj[4] = dB.x; dj[5] = dB.y; dj[6] = dB.z; dj[7] = dB.w;

  const float* erow0 = e + ((size_t)(b * cT + t0)) * cJ + lane * 8;
  uchar_t* outb = Hbf8 + (size_t)bm * 65536 + lane * 32;

  for (int mg = 0; mg < 8; mg++){
#pragma unroll
    for (int rr = 0; rr < 4; rr++){
      int rloc = wid * 4 + rr;
      const float* ep = erow0 + ((size_t)(mg * 16 + rloc)) * cJ;
      float4 e0 = *(const float4*)ep;
      float4 e1 = *(const float4*)(ep + 4);
      int v0 = pk8(tanh_fast(e0.x + dj[0]), tanh_fast(e0.y + dj[1]),
                   tanh_fast(e0.z + dj[2]), tanh_fast(e0.w + dj[3]));
      int v1 = pk8(tanh_fast(e1.x + dj[4]), tanh_fast(e1.y + dj[5]),
                   tanh_fast(e1.z + dj[6]), tanh_fast(e1.w + dj[7]));
      uint2 pk; pk.x = (unsigned)v0; pk.y = (unsigned)v1;
      *(uint2*)(sH + rloc * 520 + lane * 8) = pk;
    }
    __syncthreads();
    // kq = wid: lane reads 32B of row c16 at byte offset wid*128 + quad*32 (8B-aligned)
    {
      const uchar_t* src = sH + c16 * 520 + wid * 128 + quad * 32;
      uint2 q0 = *(const uint2*)(src + 0);
      uint2 q1 = *(const uint2*)(src + 8);
      uint2 q2 = *(const uint2*)(src + 16);
      uint2 q3 = *(const uint2*)(src + 24);
      uchar_t* dst = outb + (((size_t)wid * 8 + mg) * 64) * 32;
      uint4 lo; lo.x = q0.x; lo.y = q0.y; lo.z = q1.x; lo.w = q1.y;
      uint4 hi; hi.x = q2.x; hi.y = q2.y; hi.z = q3.x; hi.w = q3.y;
      *(uint4*)dst = lo;
      *(uint4*)(dst + 16) = hi;
    }
    __syncthreads();
  }
}

// ------------- joint GEMM, MX-scaled fp8 K=128 (2x pipe rate), 64x64 wave tile -------------
// r16 post-mortem: (256,3) capped regs at ~170 < 64 acc + 64 v8i32 inputs + addr
// -> spill (WRITE 469 MB, 280 us) despite CORRECT numerics (absmax 0.0).
// (256,2) -> ~256-reg cap; ~165 needed fits. MFMA issue floor halves vs K=32 fp8.
__global__ __launch_bounds__(256, 2) void k_joint(
    const uchar_t* __restrict__ Hbf8, const uchar_t* __restrict__ WTf8,
    const float* __restrict__ b_out, const int* __restrict__ targets,
    float* __restrict__ ps,                       // [8][cM]
    float* __restrict__ blank_g, float* __restrict__ lbl_g)
{
  __shared__ float redS[2][128];

  int tid = threadIdx.x;
  int wid = tid >> 6, lane = tid & 63;
  int quad = lane >> 4, c16 = lane & 15;
  int wm = wid & 1, wn = wid >> 1;
  int bid = blockIdx.x;
  int bm = ((bid >> 6) << 3) + (bid & 7);
  int bn = (bid >> 3) & 7;                       // 128-col strip
  int bu = bm >> 1, thalf = bm & 1;
  int b = bu / cU1, u = bu - b * cU1;
  int tg = (u < cU) ? targets[b * cU + u] : -1;
  int lin0 = bu * cT + thalf * 128;              // (b,u,t)-linear base

  f32x4 acc[4][4];
#pragma unroll
  for (int i = 0; i < 4; i++)
#pragma unroll
    for (int j = 0; j < 4; j++)
      acc[i][j] = (f32x4){0.f, 0.f, 0.f, 0.f};

  // A frag (kq, mg=wm*4+mt): Hbf8 + bm*65536 + ((kq*8+mg)*64+lane)*32
  const uchar_t* aP = Hbf8 + (size_t)bm * 65536 + ((size_t)(wm * 4) * 64 + lane) * 32;
  // B frag (kq, nt16=(bn&1)*8+wn*4+nt): WTf8 + bn4*131072 + ((kq*16+nt16)*64+lane)*32
  const uchar_t* bP = WTf8 + (size_t)(bn >> 1) * 131072 + ((size_t)((bn & 1) * 8 + wn * 4) * 64 + lane) * 32;

#pragma unroll
  for (int kq = 0; kq < 4; kq++){
    v8i32_t af[4], bf[4];
#pragma unroll
    for (int mt = 0; mt < 4; mt++)
      af[mt] = *(const v8i32_t*)(aP + (size_t)kq * 16384 + mt * 2048);
#pragma unroll
    for (int nt = 0; nt < 4; nt++)
      bf[nt] = *(const v8i32_t*)(bP + (size_t)kq * 32768 + nt * 2048);
#pragma unroll
    for (int mt = 0; mt < 4; mt++)
#pragma unroll
      for (int nt = 0; nt < 4; nt++)
        acc[mt][nt] = __builtin_amdgcn_mfma_scale_f32_16x16x128_f8f6f4(
            af[mt], bf[nt], acc[mt][nt], 0, 0, 0, 0x7F7F7F7F, 0, 0x7F7F7F7F);
  }

  float bv[4];
#pragma unroll
  for (int nt = 0; nt < 4; nt++) bv[nt] = b_out[bn * 128 + (wn * 4 + nt) * 16 + c16];

  bool ownL = (tg >= 0) && ((tg >> 7) == bn) && (((tg >> 6) & 1) == wn);
  int ntO = (tg >> 4) & 3;
  int tgc = tg & 15;
  const float descale = 1.f / 32.f;     // undo the *32 on W_out fp8

#pragma unroll
  for (int mt = 0; mt < 4; mt++){
#pragma unroll
    for (int r = 0; r < 4; r++){
      int rl = wm * 64 + mt * 16 + quad * 4 + r;  // C/D: col=lane&15, row=quad*4+reg (m89)
      float l[4];
#pragma unroll
      for (int nt = 0; nt < 4; nt++) l[nt] = fmaf(acc[mt][nt][r], descale, bv[nt]);
      if (bn == 0 && wn == 0 && c16 == 0) blank_g[lin0 + rl] = l[0];
      if (ownL && c16 == tgc){
        float v = l[0];
#pragma unroll
        for (int k = 1; k < 4; k++) v = (ntO == k) ? l[k] : v;
        lbl_g[lin0 + rl] = v;
      }
      float s = __expf(l[0]) + __expf(l[1]) + __expf(l[2]) + __expf(l[3]);
      s += __shfl_xor(s, 1, 64);
      s += __shfl_xor(s, 2, 64);
      s += __shfl_xor(s, 4, 64);
      s += __shfl_xor(s, 8, 64);
      if (c16 == 0) redS[wn][rl] = s;
    }
  }
  __syncthreads();
  if (tid < 128)
    ps[(size_t)bn * cM + lin0 + tid] = redS[0][tid] + redS[1][tid];
}

// ------------- parallel lse merge: 8 ps planes -> blankd/lbld -------------
__global__ __launch_bounds__(256) void k_lse(
    const float* __restrict__ ps, const float* __restrict__ blank_g,
    const float* __restrict__ lbl_g,
    float* __restrict__ blankd, float* __restrict__ lbld)
{
  int cell = blockIdx.x * 256 + threadIdx.x;   // 66560 = 260*256
  float S = 0.f;
#pragma unroll
  for (int p = 0; p < 8; p++) S += ps[(size_t)p * cM + cell];
  float lse = __logf(S);
  int u = (cell % cTU) >> 8;
  blankd[cell] = blank_g[cell] - lse;
  lbld[cell] = (u < cU) ? (lbl_g[cell] - lse) : NEGF;
}

// ------------- RNN-T alpha DP: SKIP-2 diagonal steps (r15-verified) -------------
__global__ __launch_bounds__(256) void k_dp(
    const float* __restrict__ blankd, const float* __restrict__ lbld,
    const int* __restrict__ in_len, const int* __restrict__ tgt_len,
    float* __restrict__ afin)
{
  __shared__ float sbb[cTU];   // 65 KB, (u,t): index u*256+t
  __shared__ float slb[cTU];   // 65 KB
  __shared__ float sS[256];    // alpha[t][63] history (lane 63)
  int b = blockIdx.x;
  int tl  = tgt_len[b];                // 32..64
  size_t base = (size_t)b * cTU;
  for (int i = threadIdx.x; i < cTU / 4; i += 256){
    ((float4*)sbb)[i] = ((const float4*)(blankd + base))[i];
    float4 v = ((const float4*)(lbld + base))[i];
    int row = (i * 4) >> 8;            // float4 never crosses a 256-elem row
    if (row >= tl){ v.x = NEGF; v.y = NEGF; v.z = NEGF; v.w = NEGF; }
    ((float4*)slb)[i] = v;
  }
  __syncthreads();
  if (threadIdx.x >= 64) return;

  int u = threadIdx.x;                 // 0..63
  int til = in_len[b] - 1;
  bool cap64 = (tl == 64);
  bool isTL = (u == tl);
  const float* pbu  = sbb + (u << 8);
  const float* pbu1 = sbb + (((u >= 1) ? u - 1 : 0) << 8);
  const float* plu1 = slb + (((u >= 1) ? u - 1 : 0) << 8);
  const float* plu2 = slb + (((u >= 2) ? u - 2 : 0) << 8);
  bool u1 = (u >= 1), u2 = (u >= 2);
  float fb = pbu[til];                 // blank at (u, til); used by lane tl only

  float A = (u == 0) ? 0.f : NEGF;     // alpha on even diagonal d = 2g
  float res = 0.f;

  auto ld = [&](const float* p, int i, bool ok) -> float {
    bool v = ok & (i >= 0) & (i <= 255);
    int ic = (i < 0) ? 0 : ((i > 255) ? 255 : i);
    float x = p[ic];
    return v ? x : NEGF;
  };

  int i0 = -u;
  float o0 = ld(pbu,  i0,     true);   // bb[t-2][u]
  float o1 = ld(pbu,  i0 + 1, true);   // bb[t-1][u]
  float o2 = ld(plu1, i0 + 1, u1);     // lb[t-1][u-1]
  float o3 = ld(pbu1, i0 + 1, u1);     // bb[t-1][u-1]
  float o4 = ld(plu1, i0 + 2, u1);     // lb[t][u-1]
  float o5 = ld(plu2, i0 + 2, u2);     // lb[t][u-2]

  for (int g = 0; g < 159; g++){
    float c0 = o0, c1 = o1, c2 = o2, c3 = o3, c4 = o4, c5 = o5;
    int i0n = i0 + 2;
    o0 = ld(pbu,  i0n,     true);
    o1 = ld(pbu,  i0n + 1, true);
    o2 = ld(plu1, i0n + 1, u1);
    o3 = ld(pbu1, i0n + 1, u1);
    o4 = ld(plu1, i0n + 2, u1);
    o5 = ld(plu2, i0n + 2, u2);

    float up1 = __shfl_up(A, 1, 64);
    float up2 = __shfl_up(A, 2, 64);

    float C0 = c0 + c1;
    float C1 = logadd(c2 + c1, c3 + c4);
    float C2 = c5 + c4;

    bool tv1 = (i0 + 1 >= 0) & (i0 + 1 <= 255);
    float Amid = logadd(A + c0, up1 + c2);
    Amid = tv1 ? Amid : NEGF;
    bool tv2 = (i0 + 2 >= 0) & (i0 + 2 <= 255);
    float Anew = logadd(logadd(A + C0, up1 + C1), up2 + C2);
    Anew = tv2 ? Anew : NEGF;

    if (isTL && (i0 + 1) == til) res = Amid + fb;
    if (isTL && (i0 + 2) == til) res = Anew + fb;
    if (u == 63){
      if (tv1) sS[i0 + 1] = Amid;
      if (tv2) sS[i0 + 2] = Anew;
    }
    A = Anew;
    i0 = i0n;
  }

  if (cap64){
    const float* pb64 = sbb + (64 << 8);
    const float* pl63 = slb + (63 << 8);
    float A64 = sS[0] + pl63[0];       // alpha[0][64]
    for (int t = 1; t <= til; t++)
      A64 = logadd(A64 + pb64[t - 1], sS[t] + pl63[t]);
    if (u == 0) res = A64 + pb64[til];
  }

  res += __shfl_xor(res, 1, 64);
  res += __shfl_xor(res, 2, 64);
  res += __shfl_xor(res, 4, 64);
  res += __shfl_xor(res, 8, 64);
  res += __shfl_xor(res, 16, 64);
  res += __shfl_xor(res, 32, 64);
  if (u == 0) afin[b] = res;
}

__global__ void k_final(const float* __restrict__ afin, float* __restrict__ out){
  if (threadIdx.x == 0)
    out[0] = -0.25f * (afin[0] + afin[1] + afin[2] + afin[3]);
}

extern "C" void kernel_launch(void* const* d_in, const int* in_sizes, int n_in,
                              void* d_out, int out_size, void* d_ws, size_t ws_size,
                              hipStream_t stream)
{
  (void)in_sizes; (void)n_in; (void)out_size; (void)ws_size;
  const float* inputs = (const float*)d_in[0];   // (4,256,80)
  const float* W_enc  = (const float*)d_in[1];   // (80,512)
  const float* emb    = (const float*)d_in[2];   // (1024,512)
  const float* W_jenc = (const float*)d_in[3];   // (512,512)
  const float* W_jdec = (const float*)d_in[4];   // (512,512)
  const float* b_j    = (const float*)d_in[5];   // (512)
  const float* W_out  = (const float*)d_in[6];   // (512,1024)
  const float* b_out  = (const float*)d_in[7];   // (1024)
  const int* targets  = (const int*)d_in[8];     // (4,64)
  const int* in_len   = (const int*)d_in[9];     // (4)
  const int* tgt_len  = (const int*)d_in[10];    // (4)

  char* w = (char*)d_ws;
  auto alloc = [&](size_t bytes){ char* p = w; w += (bytes + 255) & ~(size_t)255; return p; };
  float* Wcomb   = (float*)alloc((size_t)80 * 512 * 4);
  float* e       = (float*)alloc((size_t)1024 * 512 * 4);
  float* dmatb   = (float*)alloc((size_t)260 * 512 * 4);
  float* blank_g = (float*)alloc((size_t)cM * 4);
  float* lbl_g   = (float*)alloc((size_t)cM * 4);
  float* ps      = (float*)alloc((size_t)8 * cM * 4);
  float* blankd  = (float*)alloc((size_t)cM * 4);
  float* lbld    = (float*)alloc((size_t)cM * 4);
  float* afin    = (float*)alloc(256);
  uchar_t* Hbf8  = (uchar_t*)alloc((size_t)520 * 65536);
  uchar_t* WTf8  = (uchar_t*)alloc((size_t)4 * 131072);

  k_pre<<<186, 256, 0, stream>>>(W_enc, W_jenc, Wcomb, emb, targets, W_jdec, b_j, dmatb,
                                 W_out, WTf8);
  k_gemm_e<<<dim3(2, 256), 256, 0, stream>>>(inputs, Wcomb, e);
  k_hf<<<520, 256, 0, stream>>>(e, dmatb, Hbf8);
  k_joint<<<4160, 256, 0, stream>>>(Hbf8, WTf8, b_out, targets, ps, blank_g, lbl_g);
  k_lse<<<260, 256, 0, stream>>>(ps, blank_g, lbl_g, blankd, lbld);
  k_dp<<<4, 256, 0, stream>>>(blankd, lbld, in_len, tgt_len, afin);
  k_final<<<1, 64, 0, stream>>>(afin, (float*)d_out);
}

// Round 18
// 246.718 us; speedup vs baseline: 1.8840x; 1.1696x over previous
//
#include <hip/hip_runtime.h>
#include <stdint.h>

#define NEGF (-1e30f)

typedef unsigned short ushort_t;
typedef unsigned char uchar_t;
typedef __attribute__((ext_vector_type(2))) long v2i64;
typedef __attribute__((ext_vector_type(4))) float f32x4;

constexpr int cB = 4, cT = 256, cU = 64, cU1 = 65, cV = 1024, cF = 80, cH = 512, cJ = 512;
constexpr int cM = cB * cT * cU1; // 66560
constexpr int cTU = cT * cU1;     // 16640 (per-batch (u,t) plane: u*256+t)

// Padé(2,2) tanh + clamp: max err ~0.016, far below fp8-e4m3 half-step; no v_exp.
__device__ __forceinline__ float tanh_fast(float x){
  float t = x * x;
  float num = x * (27.f + t);
  float den = fmaf(9.f, t, 27.f);
  float r = num * __builtin_amdgcn_rcpf(den);
  return fminf(1.f, fmaxf(-1.f, r));
}

__device__ __forceinline__ float logadd(float x, float y){
  float m = fmaxf(x, y);
  return m + __logf(1.f + __expf(-fabsf(x - y)));
}

__device__ __forceinline__ int pk8(float a, float b, float c, float d){
  int v = __builtin_amdgcn_cvt_pk_fp8_f32(a, b, 0, false);
  v = __builtin_amdgcn_cvt_pk_fp8_f32(c, d, v, true);
  return v;
}

// ------------- fused prologue: 4 independent jobs in one dispatch -------------
// bid 0..39   : Wcomb(80,512)  = W_enc @ W_jenc
// bid 40..169 : dmatb(260,512) = emb[padded] @ W_jdec + b_j
// bid 170..201: WTf8 fp8 fragment-order transpose of 32*W_out (2-ks-packed, K=32)
// bid 202..266: zero S[cM] (exp-sum accumulator for k_joint's atomics)
__global__ __launch_bounds__(256) void k_pre(
    const float* __restrict__ W_enc, const float* __restrict__ W_jenc,
    float* __restrict__ Wcomb,
    const float* __restrict__ emb, const int* __restrict__ targets,
    const float* __restrict__ W_jdec, const float* __restrict__ b_j,
    float* __restrict__ dmatb,
    const float* __restrict__ W_out, uchar_t* __restrict__ WTf8,
    float* __restrict__ S)
{
  __shared__ float sA[4][512];
  int bid = blockIdx.x;
  int tid = threadIdx.x;

  if (bid < 170){
    bool isW = (bid < 40);
    int id = isW ? bid : bid - 40;
    int bx = id & 1, by = id >> 1;
    int m0 = by * 4;
    int col = bx * 256 + tid;
    const float* Bm = isW ? W_jenc : W_jdec;
    for (int i = tid; i < 4 * 512; i += 256){
      int r = i >> 9, c = i & 511;
      if (isW){
        sA[r][c] = W_enc[(size_t)(m0 + r) * 512 + c];
      } else {
        int row = m0 + r;
        int b = row / cU1, u = row % cU1;
        int src = (u == 0) ? 0 : targets[b * cU + (u - 1)];
        sA[r][c] = emb[(size_t)src * cH + c];
      }
    }
    __syncthreads();
    float a0 = 0.f, a1 = 0.f, a2 = 0.f, a3 = 0.f;
#pragma unroll 8
    for (int k = 0; k < 512; k++){
      float bv = Bm[(size_t)k * cJ + col];
      a0 = fmaf(sA[0][k], bv, a0);
      a1 = fmaf(sA[1][k], bv, a1);
      a2 = fmaf(sA[2][k], bv, a2);
      a3 = fmaf(sA[3][k], bv, a3);
    }
    float bb = isW ? 0.f : b_j[col];
    float* C = isW ? Wcomb : dmatb;
    C[(size_t)(m0 + 0) * cJ + col] = a0 + bb;
    C[(size_t)(m0 + 1) * cJ + col] = a1 + bb;
    C[(size_t)(m0 + 2) * cJ + col] = a2 + bb;
    C[(size_t)(m0 + 3) * cJ + col] = a3 + bb;
  } else if (bid < 202){
    // WTf8[((bn4*8+ksp)*16 + nt16)*1024 + lane*16]: 16 B = frag(ks=2ksp) || frag(ks=2ksp+1)
    int id = bid - 170;                  // 0..31
    int bn = id & 3, ksp = id >> 2;      // ksp 0..7
    int lane = tid & 63, nth = tid >> 6;
    int c16 = lane & 15, quad = lane >> 4;
    int jA = ksp * 64 + quad * 8;
#pragma unroll
    for (int i = 0; i < 4; i++){
      int nt16 = nth * 4 + i;
      int n = bn * 256 + nt16 * 16 + c16;
      unsigned int p[4];
#pragma unroll
      for (int h = 0; h < 4; h++){
        int j0 = jA + (h >> 1) * 32 + (h & 1) * 4;
        float w0 = W_out[(size_t)(j0 + 0) * cV + n] * 32.f;
        float w1 = W_out[(size_t)(j0 + 1) * cV + n] * 32.f;
        float w2 = W_out[(size_t)(j0 + 2) * cV + n] * 32.f;
        float w3 = W_out[(size_t)(j0 + 3) * cV + n] * 32.f;
        p[h] = (unsigned)pk8(w0, w1, w2, w3);
      }
      uint4 pack; pack.x = p[0]; pack.y = p[1]; pack.z = p[2]; pack.w = p[3];
      *(uint4*)(WTf8 + (((size_t)(bn * 8 + ksp) * 16 + nt16) * 64 + lane) * 16) = pack;
    }
  } else {
    // zero S: 65 blocks x 256 thr x 4 floats = 66560
    int i = (bid - 202) * 1024 + tid * 4;
    float4 z; z.x = 0.f; z.y = 0.f; z.z = 0.f; z.w = 0.f;
    *(float4*)(S + i) = z;
  }
}

// ------------- e = inputs @ Wcomb  (K=80), 4 rows/block -------------
__global__ void k_gemm_e(const float* __restrict__ A, const float* __restrict__ Bm,
                         float* __restrict__ C){
  __shared__ float sA[4][80];
  int m0 = blockIdx.y * 4;
  int col = blockIdx.x * 256 + threadIdx.x;
  for (int i = threadIdx.x; i < 4 * 80; i += 256)
    sA[i / 80][i % 80] = A[(size_t)(m0 + i / 80) * 80 + (i % 80)];
  __syncthreads();
  float a0 = 0.f, a1 = 0.f, a2 = 0.f, a3 = 0.f;
#pragma unroll 8
  for (int k = 0; k < 80; k++){
    float bv = Bm[(size_t)k * cJ + col];
    a0 = fmaf(sA[0][k], bv, a0);
    a1 = fmaf(sA[1][k], bv, a1);
    a2 = fmaf(sA[2][k], bv, a2);
    a3 = fmaf(sA[3][k], bv, a3);
  }
  C[(size_t)(m0 + 0) * cJ + col] = a0;
  C[(size_t)(m0 + 1) * cJ + col] = a1;
  C[(size_t)(m0 + 2) * cJ + col] = a2;
  C[(size_t)(m0 + 3) * cJ + col] = a3;
}

// ------------- H fp8 fragment-order, t-minor, coalesced via LDS bounce -------------
__global__ __launch_bounds__(256) void k_hf(const float* __restrict__ e,
                                            const float* __restrict__ dmatb,
                                            uchar_t* __restrict__ Hbf8){
  __shared__ uchar_t sH[16 * 520];    // 16 rows x 512 B, pad 8 B
  int tid = threadIdx.x;
  int wid = tid >> 6, lane = tid & 63;
  int c16 = lane & 15, quad = lane >> 4;
  int bm = blockIdx.x;
  int bu = bm >> 1, thalf = bm & 1;
  int b = bu / cU1;
  int t0 = thalf * 128;

  float dj[8];
  const float4* dp = (const float4*)(dmatb + (size_t)bu * cJ + lane * 8);
  float4 dA = dp[0], dB = dp[1];
  dj[0] = dA.x; dj[1] = dA.y; dj[2] = dA.z; dj[3] = dA.w;
  dj[4] = dB.x; dj[5] = dB.y; dj[6] = dB.z; dj[7] = dB.w;

  const float* erow0 = e + ((size_t)(b * cT + t0)) * cJ + lane * 8;
  uchar_t* outb = Hbf8 + (size_t)bm * 65536 + lane * 16;

  for (int mg = 0; mg < 8; mg++){
#pragma unroll
    for (int rr = 0; rr < 4; rr++){
      int rloc = wid * 4 + rr;
      const float* ep = erow0 + ((size_t)(mg * 16 + rloc)) * cJ;
      float4 e0 = *(const float4*)ep;
      float4 e1 = *(const float4*)(ep + 4);
      int v0 = pk8(tanh_fast(e0.x + dj[0]), tanh_fast(e0.y + dj[1]),
                   tanh_fast(e0.z + dj[2]), tanh_fast(e0.w + dj[3]));
      int v1 = pk8(tanh_fast(e1.x + dj[4]), tanh_fast(e1.y + dj[5]),
                   tanh_fast(e1.z + dj[6]), tanh_fast(e1.w + dj[7]));
      uint2 pk; pk.x = (unsigned)v0; pk.y = (unsigned)v1;
      *(uint2*)(sH + rloc * 520 + lane * 8) = pk;
    }
    __syncthreads();
#pragma unroll
    for (int q = 0; q < 2; q++){
      int ksp = wid * 2 + q;
      uint2 lo = *(const uint2*)(sH + c16 * 520 + ksp * 64 + quad * 8);
      uint2 hi = *(const uint2*)(sH + c16 * 520 + ksp * 64 + 32 + quad * 8);
      uint4 pack; pack.x = lo.x; pack.y = lo.y; pack.z = hi.x; pack.w = hi.y;
      *(uint4*)(outb + ((size_t)ksp * 8 + mg) * 1024) = pack;
    }
    __syncthreads();
  }
}

// ------------- joint GEMM fp8 K=32: 64x64 wave tile, register-direct, 3 blocks/CU -------------
// r15-proven config (VGPR 60 + 64 AGPR, no spill, 71 us). Epilogue exp-sum partials
// now atomicAdd into S[cM] (zeroed by k_pre; stream order guarantees precedence).
__global__ __launch_bounds__(256, 3) void k_joint(
    const uchar_t* __restrict__ Hbf8, const uchar_t* __restrict__ WTf8,
    const float* __restrict__ b_out, const int* __restrict__ targets,
    float* __restrict__ S,
    float* __restrict__ blank_g, float* __restrict__ lbl_g)
{
  __shared__ float redS[2][128];

  int tid = threadIdx.x;
  int wid = tid >> 6, lane = tid & 63;
  int quad = lane >> 4, c16 = lane & 15;
  int wm = wid & 1, wn = wid >> 1;
  int bid = blockIdx.x;
  int bm = ((bid >> 6) << 3) + (bid & 7);
  int bn = (bid >> 3) & 7;                       // 128-col strip
  int bu = bm >> 1, thalf = bm & 1;
  int b = bu / cU1, u = bu - b * cU1;
  int tg = (u < cU) ? targets[b * cU + u] : -1;
  int lin0 = bu * cT + thalf * 128;              // (b,u,t)-linear base

  f32x4 acc[4][4];
#pragma unroll
  for (int i = 0; i < 4; i++)
#pragma unroll
    for (int j = 0; j < 4; j++)
      acc[i][j] = (f32x4){0.f, 0.f, 0.f, 0.f};

  const uchar_t* aP = Hbf8 + (size_t)bm * 65536 + (wm * 4) * 1024 + lane * 16;
  const uchar_t* bP = WTf8 + (size_t)(bn >> 1) * 131072 + ((bn & 1) * 8 + wn * 4) * 1024 + lane * 16;

#pragma unroll
  for (int ksp = 0; ksp < 8; ksp++){
    v2i64 af[4], bf[4];
#pragma unroll
    for (int mt = 0; mt < 4; mt++)
      af[mt] = *(const v2i64*)(aP + (size_t)ksp * 8192 + mt * 1024);
#pragma unroll
    for (int nt = 0; nt < 4; nt++)
      bf[nt] = *(const v2i64*)(bP + (size_t)ksp * 16384 + nt * 1024);
#pragma unroll
    for (int h = 0; h < 2; h++)
#pragma unroll
      for (int mt = 0; mt < 4; mt++)
#pragma unroll
        for (int nt = 0; nt < 4; nt++)
          acc[mt][nt] = __builtin_amdgcn_mfma_f32_16x16x32_fp8_fp8(af[mt][h], bf[nt][h], acc[mt][nt], 0, 0, 0);
  }

  float bv[4];
#pragma unroll
  for (int nt = 0; nt < 4; nt++) bv[nt] = b_out[bn * 128 + (wn * 4 + nt) * 16 + c16];

  bool ownL = (tg >= 0) && ((tg >> 7) == bn) && (((tg >> 6) & 1) == wn);
  int ntO = (tg >> 4) & 3;
  int tgc = tg & 15;
  const float descale = 1.f / 32.f;     // undo the *32 on W_out fp8

#pragma unroll
  for (int mt = 0; mt < 4; mt++){
#pragma unroll
    for (int r = 0; r < 4; r++){
      int rl = wm * 64 + mt * 16 + quad * 4 + r;  // C/D: col=lane&15, row=quad*4+reg (m89)
      float l[4];
#pragma unroll
      for (int nt = 0; nt < 4; nt++) l[nt] = fmaf(acc[mt][nt][r], descale, bv[nt]);
      if (bn == 0 && wn == 0 && c16 == 0) blank_g[lin0 + rl] = l[0];
      if (ownL && c16 == tgc){
        float v = l[0];
#pragma unroll
        for (int k = 1; k < 4; k++) v = (ntO == k) ? l[k] : v;
        lbl_g[lin0 + rl] = v;
      }
      float s = __expf(l[0]) + __expf(l[1]) + __expf(l[2]) + __expf(l[3]);
      s += __shfl_xor(s, 1, 64);
      s += __shfl_xor(s, 2, 64);
      s += __shfl_xor(s, 4, 64);
      s += __shfl_xor(s, 8, 64);
      if (c16 == 0) redS[wn][rl] = s;
    }
  }
  __syncthreads();
  if (tid < 128)
    atomicAdd(&S[lin0 + tid], redS[0][tid] + redS[1][tid]);
}

// ------------- RNN-T alpha DP: SKIP-2 diagonal steps (r15-verified), lse fused in staging -------------
__global__ __launch_bounds__(256) void k_dp(
    const float* __restrict__ blank_g, const float* __restrict__ lbl_g,
    const float* __restrict__ S,
    const int* __restrict__ in_len, const int* __restrict__ tgt_len,
    float* __restrict__ afin)
{
  __shared__ float sbb[cTU];   // 65 KB, (u,t): index u*256+t
  __shared__ float slb[cTU];   // 65 KB
  __shared__ float sS[256];    // alpha[t][63] history (lane 63)
  int b = blockIdx.x;
  int tl  = tgt_len[b];                // 32..64
  size_t base = (size_t)b * cTU;
  for (int i = threadIdx.x; i < cTU / 4; i += 256){
    float4 bg = ((const float4*)(blank_g + base))[i];
    float4 lg = ((const float4*)(lbl_g + base))[i];
    float4 sv = ((const float4*)(S + base))[i];
    float4 ls;
    ls.x = __logf(sv.x); ls.y = __logf(sv.y); ls.z = __logf(sv.z); ls.w = __logf(sv.w);
    float4 ob;
    ob.x = bg.x - ls.x; ob.y = bg.y - ls.y; ob.z = bg.z - ls.z; ob.w = bg.w - ls.w;
    ((float4*)sbb)[i] = ob;
    int row = (i * 4) >> 8;            // float4 never crosses a 256-elem row
    float4 ol;
    if (row >= tl){ ol.x = NEGF; ol.y = NEGF; ol.z = NEGF; ol.w = NEGF; }
    else { ol.x = lg.x - ls.x; ol.y = lg.y - ls.y; ol.z = lg.z - ls.z; ol.w = lg.w - ls.w; }
    ((float4*)slb)[i] = ol;
  }
  __syncthreads();
  if (threadIdx.x >= 64) return;

  int u = threadIdx.x;                 // 0..63
  int til = in_len[b] - 1;
  bool cap64 = (tl == 64);
  bool isTL = (u == tl);
  const float* pbu  = sbb + (u << 8);
  const float* pbu1 = sbb + (((u >= 1) ? u - 1 : 0) << 8);
  const float* plu1 = slb + (((u >= 1) ? u - 1 : 0) << 8);
  const float* plu2 = slb + (((u >= 2) ? u - 2 : 0) << 8);
  bool u1 = (u >= 1), u2 = (u >= 2);
  float fb = pbu[til];                 // blank at (u, til); used by lane tl only

  float A = (u == 0) ? 0.f : NEGF;     // alpha on even diagonal d = 2g
  float res = 0.f;

  auto ld = [&](const float* p, int i, bool ok) -> float {
    bool v = ok & (i >= 0) & (i <= 255);
    int ic = (i < 0) ? 0 : ((i > 255) ? 255 : i);
    float x = p[ic];
    return v ? x : NEGF;
  };

  int i0 = -u;
  float o0 = ld(pbu,  i0,     true);   // bb[t-2][u]
  float o1 = ld(pbu,  i0 + 1, true);   // bb[t-1][u]
  float o2 = ld(plu1, i0 + 1, u1);     // lb[t-1][u-1]
  float o3 = ld(pbu1, i0 + 1, u1);     // bb[t-1][u-1]
  float o4 = ld(plu1, i0 + 2, u1);     // lb[t][u-1]
  float o5 = ld(plu2, i0 + 2, u2);     // lb[t][u-2]

  for (int g = 0; g < 159; g++){
    float c0 = o0, c1 = o1, c2 = o2, c3 = o3, c4 = o4, c5 = o5;
    int i0n = i0 + 2;
    o0 = ld(pbu,  i0n,     true);
    o1 = ld(pbu,  i0n + 1, true);
    o2 = ld(plu1, i0n + 1, u1);
    o3 = ld(pbu1, i0n + 1, u1);
    o4 = ld(plu1, i0n + 2, u1);
    o5 = ld(plu2, i0n + 2, u2);

    float up1 = __shfl_up(A, 1, 64);
    float up2 = __shfl_up(A, 2, 64);

    float C0 = c0 + c1;
    float C1 = logadd(c2 + c1, c3 + c4);
    float C2 = c5 + c4;

    bool tv1 = (i0 + 1 >= 0) & (i0 + 1 <= 255);
    float Amid = logadd(A + c0, up1 + c2);
    Amid = tv1 ? Amid : NEGF;
    bool tv2 = (i0 + 2 >= 0) & (i0 + 2 <= 255);
    float Anew = logadd(logadd(A + C0, up1 + C1), up2 + C2);
    Anew = tv2 ? Anew : NEGF;

    if (isTL && (i0 + 1) == til) res = Amid + fb;
    if (isTL && (i0 + 2) == til) res = Anew + fb;
    if (u == 63){
      if (tv1) sS[i0 + 1] = Amid;
      if (tv2) sS[i0 + 2] = Anew;
    }
    A = Anew;
    i0 = i0n;
  }

  if (cap64){
    const float* pb64 = sbb + (64 << 8);
    const float* pl63 = slb + (63 << 8);
    float A64 = sS[0] + pl63[0];       // alpha[0][64]
    for (int t = 1; t <= til; t++)
      A64 = logadd(A64 + pb64[t - 1], sS[t] + pl63[t]);
    if (u == 0) res = A64 + pb64[til];
  }

  res += __shfl_xor(res, 1, 64);
  res += __shfl_xor(res, 2, 64);
  res += __shfl_xor(res, 4, 64);
  res += __shfl_xor(res, 8, 64);
  res += __shfl_xor(res, 16, 64);
  res += __shfl_xor(res, 32, 64);
  if (u == 0) afin[b] = res;
}

__global__ void k_final(const float* __restrict__ afin, float* __restrict__ out){
  if (threadIdx.x == 0)
    out[0] = -0.25f * (afin[0] + afin[1] + afin[2] + afin[3]);
}

extern "C" void kernel_launch(void* const* d_in, const int* in_sizes, int n_in,
                              void* d_out, int out_size, void* d_ws, size_t ws_size,
                              hipStream_t stream)
{
  (void)in_sizes; (void)n_in; (void)out_size; (void)ws_size;
  const float* inputs = (const float*)d_in[0];   // (4,256,80)
  const float* W_enc  = (const float*)d_in[1];   // (80,512)
  const float* emb    = (const float*)d_in[2];   // (1024,512)
  const float* W_jenc = (const float*)d_in[3];   // (512,512)
  const float* W_jdec = (const float*)d_in[4];   // (512,512)
  const float* b_j    = (const float*)d_in[5];   // (512)
  const float* W_out  = (const float*)d_in[6];   // (512,1024)
  const float* b_out  = (const float*)d_in[7];   // (1024)
  const int* targets  = (const int*)d_in[8];     // (4,64)
  const int* in_len   = (const int*)d_in[9];     // (4)
  const int* tgt_len  = (const int*)d_in[10];    // (4)

  char* w = (char*)d_ws;
  auto alloc = [&](size_t bytes){ char* p = w; w += (bytes + 255) & ~(size_t)255; return p; };
  float* Wcomb   = (float*)alloc((size_t)80 * 512 * 4);
  float* e       = (float*)alloc((size_t)1024 * 512 * 4);
  float* dmatb   = (float*)alloc((size_t)260 * 512 * 4);
  float* blank_g = (float*)alloc((size_t)cM * 4);
  float* lbl_g   = (float*)alloc((size_t)cM * 4);
  float* S       = (float*)alloc((size_t)cM * 4);
  float* afin    = (float*)alloc(256);
  uchar_t* Hbf8  = (uchar_t*)alloc((size_t)520 * 65536);
  uchar_t* WTf8  = (uchar_t*)alloc((size_t)4 * 131072);

  k_pre<<<267, 256, 0, stream>>>(W_enc, W_jenc, Wcomb, emb, targets, W_jdec, b_j, dmatb,
                                 W_out, WTf8, S);
  k_gemm_e<<<dim3(2, 256), 256, 0, stream>>>(inputs, Wcomb, e);
  k_hf<<<520, 256, 0, stream>>>(e, dmatb, Hbf8);
  k_joint<<<4160, 256, 0, stream>>>(Hbf8, WTf8, b_out, targets, S, blank_g, lbl_g);
  k_dp<<<4, 256, 0, stream>>>(blank_g, lbl_g, S, in_len, tgt_len, afin);
  k_final<<<1, 64, 0, stream>>>(afin, (float*)d_out);
}

// Round 19
// 243.869 us; speedup vs baseline: 1.9060x; 1.0117x over previous
//
#include <hip/hip_runtime.h>
#include <stdint.h>

#define NEGF (-1e30f)

typedef unsigned short ushort_t;
typedef unsigned char uchar_t;
typedef __attribute__((ext_vector_type(2))) long v2i64;
typedef __attribute__((ext_vector_type(4))) float f32x4;

constexpr int cB = 4, cT = 256, cU = 64, cU1 = 65, cV = 1024, cF = 80, cH = 512, cJ = 512;
constexpr int cM = cB * cT * cU1; // 66560
constexpr int cTU = cT * cU1;     // 16640 (per-batch (u,t) plane: u*256+t)

// Padé(2,2) tanh + clamp: max err ~0.016, far below fp8-e4m3 half-step; no v_exp.
__device__ __forceinline__ float tanh_fast(float x){
  float t = x * x;
  float num = x * (27.f + t);
  float den = fmaf(9.f, t, 27.f);
  float r = num * __builtin_amdgcn_rcpf(den);
  return fminf(1.f, fmaxf(-1.f, r));
}

__device__ __forceinline__ float logadd(float x, float y){
  float m = fmaxf(x, y);
  return m + __logf(1.f + __expf(-fabsf(x - y)));
}

__device__ __forceinline__ int pk8(float a, float b, float c, float d){
  int v = __builtin_amdgcn_cvt_pk_fp8_f32(a, b, 0, false);
  v = __builtin_amdgcn_cvt_pk_fp8_f32(c, d, v, true);
  return v;
}

// ------------- fused prologue: 4 independent jobs in one dispatch -------------
// bid 0..39   : Wcomb(80,512)  = W_enc @ W_jenc
// bid 40..169 : dmatb(260,512) = emb[padded] @ W_jdec + b_j
// bid 170..201: WTf8 fp8 fragment-order transpose of 32*W_out (2-ks-packed, K=32)
// bid 202..266: zero S[cM]; bid 202 also zeroes out[0] (k_dp atomic target)
__global__ __launch_bounds__(256) void k_pre(
    const float* __restrict__ W_enc, const float* __restrict__ W_jenc,
    float* __restrict__ Wcomb,
    const float* __restrict__ emb, const int* __restrict__ targets,
    const float* __restrict__ W_jdec, const float* __restrict__ b_j,
    float* __restrict__ dmatb,
    const float* __restrict__ W_out, uchar_t* __restrict__ WTf8,
    float* __restrict__ S, float* __restrict__ out_loss)
{
  __shared__ float sA[4][512];
  int bid = blockIdx.x;
  int tid = threadIdx.x;

  if (bid < 170){
    bool isW = (bid < 40);
    int id = isW ? bid : bid - 40;
    int bx = id & 1, by = id >> 1;
    int m0 = by * 4;
    int col = bx * 256 + tid;
    const float* Bm = isW ? W_jenc : W_jdec;
    for (int i = tid; i < 4 * 512; i += 256){
      int r = i >> 9, c = i & 511;
      if (isW){
        sA[r][c] = W_enc[(size_t)(m0 + r) * 512 + c];
      } else {
        int row = m0 + r;
        int b = row / cU1, u = row % cU1;
        int src = (u == 0) ? 0 : targets[b * cU + (u - 1)];
        sA[r][c] = emb[(size_t)src * cH + c];
      }
    }
    __syncthreads();
    float a0 = 0.f, a1 = 0.f, a2 = 0.f, a3 = 0.f;
#pragma unroll 8
    for (int k = 0; k < 512; k++){
      float bv = Bm[(size_t)k * cJ + col];
      a0 = fmaf(sA[0][k], bv, a0);
      a1 = fmaf(sA[1][k], bv, a1);
      a2 = fmaf(sA[2][k], bv, a2);
      a3 = fmaf(sA[3][k], bv, a3);
    }
    float bb = isW ? 0.f : b_j[col];
    float* C = isW ? Wcomb : dmatb;
    C[(size_t)(m0 + 0) * cJ + col] = a0 + bb;
    C[(size_t)(m0 + 1) * cJ + col] = a1 + bb;
    C[(size_t)(m0 + 2) * cJ + col] = a2 + bb;
    C[(size_t)(m0 + 3) * cJ + col] = a3 + bb;
  } else if (bid < 202){
    // WTf8[((bn4*8+ksp)*16 + nt16)*1024 + lane*16]: 16 B = frag(ks=2ksp) || frag(ks=2ksp+1)
    int id = bid - 170;                  // 0..31
    int bn = id & 3, ksp = id >> 2;      // ksp 0..7
    int lane = tid & 63, nth = tid >> 6;
    int c16 = lane & 15, quad = lane >> 4;
    int jA = ksp * 64 + quad * 8;
#pragma unroll
    for (int i = 0; i < 4; i++){
      int nt16 = nth * 4 + i;
      int n = bn * 256 + nt16 * 16 + c16;
      unsigned int p[4];
#pragma unroll
      for (int h = 0; h < 4; h++){
        int j0 = jA + (h >> 1) * 32 + (h & 1) * 4;
        float w0 = W_out[(size_t)(j0 + 0) * cV + n] * 32.f;
        float w1 = W_out[(size_t)(j0 + 1) * cV + n] * 32.f;
        float w2 = W_out[(size_t)(j0 + 2) * cV + n] * 32.f;
        float w3 = W_out[(size_t)(j0 + 3) * cV + n] * 32.f;
        p[h] = (unsigned)pk8(w0, w1, w2, w3);
      }
      uint4 pack; pack.x = p[0]; pack.y = p[1]; pack.z = p[2]; pack.w = p[3];
      *(uint4*)(WTf8 + (((size_t)(bn * 8 + ksp) * 16 + nt16) * 64 + lane) * 16) = pack;
    }
  } else {
    // zero S: 65 blocks x 256 thr x 4 floats = 66560
    int i = (bid - 202) * 1024 + tid * 4;
    float4 z; z.x = 0.f; z.y = 0.f; z.z = 0.f; z.w = 0.f;
    *(float4*)(S + i) = z;
    if (bid == 202 && tid == 0) out_loss[0] = 0.f;
  }
}

// ------------- e = inputs @ Wcomb  (K=80), 4 rows/block -------------
__global__ void k_gemm_e(const float* __restrict__ A, const float* __restrict__ Bm,
                         float* __restrict__ C){
  __shared__ float sA[4][80];
  int m0 = blockIdx.y * 4;
  int col = blockIdx.x * 256 + threadIdx.x;
  for (int i = threadIdx.x; i < 4 * 80; i += 256)
    sA[i / 80][i % 80] = A[(size_t)(m0 + i / 80) * 80 + (i % 80)];
  __syncthreads();
  float a0 = 0.f, a1 = 0.f, a2 = 0.f, a3 = 0.f;
#pragma unroll 8
  for (int k = 0; k < 80; k++){
    float bv = Bm[(size_t)k * cJ + col];
    a0 = fmaf(sA[0][k], bv, a0);
    a1 = fmaf(sA[1][k], bv, a1);
    a2 = fmaf(sA[2][k], bv, a2);
    a3 = fmaf(sA[3][k], bv, a3);
  }
  C[(size_t)(m0 + 0) * cJ + col] = a0;
  C[(size_t)(m0 + 1) * cJ + col] = a1;
  C[(size_t)(m0 + 2) * cJ + col] = a2;
  C[(size_t)(m0 + 3) * cJ + col] = a3;
}

// ------------- H fp8 fragment-order, t-minor, coalesced via LDS bounce -------------
__global__ __launch_bounds__(256) void k_hf(const float* __restrict__ e,
                                            const float* __restrict__ dmatb,
                                            uchar_t* __restrict__ Hbf8){
  __shared__ uchar_t sH[16 * 520];    // 16 rows x 512 B, pad 8 B
  int tid = threadIdx.x;
  int wid = tid >> 6, lane = tid & 63;
  int c16 = lane & 15, quad = lane >> 4;
  int bm = blockIdx.x;
  int bu = bm >> 1, thalf = bm & 1;
  int b = bu / cU1;
  int t0 = thalf * 128;

  float dj[8];
  const float4* dp = (const float4*)(dmatb + (size_t)bu * cJ + lane * 8);
  float4 dA = dp[0], dB = dp[1];
  dj[0] = dA.x; dj[1] = dA.y; dj[2] = dA.z; dj[3] = dA.w;
  dj[4] = dB.x; dj[5] = dB.y; dj[6] = dB.z; dj[7] = dB.w;

  const float* erow0 = e + ((size_t)(b * cT + t0)) * cJ + lane * 8;
  uchar_t* outb = Hbf8 + (size_t)bm * 65536 + lane * 16;

  for (int mg = 0; mg < 8; mg++){
#pragma unroll
    for (int rr = 0; rr < 4; rr++){
      int rloc = wid * 4 + rr;
      const float* ep = erow0 + ((size_t)(mg * 16 + rloc)) * cJ;
      float4 e0 = *(const float4*)ep;
      float4 e1 = *(const float4*)(ep + 4);
      int v0 = pk8(tanh_fast(e0.x + dj[0]), tanh_fast(e0.y + dj[1]),
                   tanh_fast(e0.z + dj[2]), tanh_fast(e0.w + dj[3]));
      int v1 = pk8(tanh_fast(e1.x + dj[4]), tanh_fast(e1.y + dj[5]),
                   tanh_fast(e1.z + dj[6]), tanh_fast(e1.w + dj[7]));
      uint2 pk; pk.x = (unsigned)v0; pk.y = (unsigned)v1;
      *(uint2*)(sH + rloc * 520 + lane * 8) = pk;
    }
    __syncthreads();
#pragma unroll
    for (int q = 0; q < 2; q++){
      int ksp = wid * 2 + q;
      uint2 lo = *(const uint2*)(sH + c16 * 520 + ksp * 64 + quad * 8);
      uint2 hi = *(const uint2*)(sH + c16 * 520 + ksp * 64 + 32 + quad * 8);
      uint4 pack; pack.x = lo.x; pack.y = lo.y; pack.z = hi.x; pack.w = hi.y;
      *(uint4*)(outb + ((size_t)ksp * 8 + mg) * 1024) = pack;
    }
    __syncthreads();
  }
}

// ------------- joint GEMM fp8 K=32: 64x64 wave tile, 3 blocks/CU, atomic-S epilogue -------------
// r18-measured <63 us (vs 71 with the 8-plane ps store). VGPR 60 + 64 AGPR, no spill.
__global__ __launch_bounds__(256, 3) void k_joint(
    const uchar_t* __restrict__ Hbf8, const uchar_t* __restrict__ WTf8,
    const float* __restrict__ b_out, const int* __restrict__ targets,
    float* __restrict__ S,
    float* __restrict__ blank_g, float* __restrict__ lbl_g)
{
  __shared__ float redS[2][128];

  int tid = threadIdx.x;
  int wid = tid >> 6, lane = tid & 63;
  int quad = lane >> 4, c16 = lane & 15;
  int wm = wid & 1, wn = wid >> 1;
  int bid = blockIdx.x;
  int bm = ((bid >> 6) << 3) + (bid & 7);
  int bn = (bid >> 3) & 7;                       // 128-col strip
  int bu = bm >> 1, thalf = bm & 1;
  int b = bu / cU1, u = bu - b * cU1;
  int tg = (u < cU) ? targets[b * cU + u] : -1;
  int lin0 = bu * cT + thalf * 128;              // (b,u,t)-linear base

  f32x4 acc[4][4];
#pragma unroll
  for (int i = 0; i < 4; i++)
#pragma unroll
    for (int j = 0; j < 4; j++)
      acc[i][j] = (f32x4){0.f, 0.f, 0.f, 0.f};

  const uchar_t* aP = Hbf8 + (size_t)bm * 65536 + (wm * 4) * 1024 + lane * 16;
  const uchar_t* bP = WTf8 + (size_t)(bn >> 1) * 131072 + ((bn & 1) * 8 + wn * 4) * 1024 + lane * 16;

#pragma unroll
  for (int ksp = 0; ksp < 8; ksp++){
    v2i64 af[4], bf[4];
#pragma unroll
    for (int mt = 0; mt < 4; mt++)
      af[mt] = *(const v2i64*)(aP + (size_t)ksp * 8192 + mt * 1024);
#pragma unroll
    for (int nt = 0; nt < 4; nt++)
      bf[nt] = *(const v2i64*)(bP + (size_t)ksp * 16384 + nt * 1024);
#pragma unroll
    for (int h = 0; h < 2; h++)
#pragma unroll
      for (int mt = 0; mt < 4; mt++)
#pragma unroll
        for (int nt = 0; nt < 4; nt++)
          acc[mt][nt] = __builtin_amdgcn_mfma_f32_16x16x32_fp8_fp8(af[mt][h], bf[nt][h], acc[mt][nt], 0, 0, 0);
  }

  float bv[4];
#pragma unroll
  for (int nt = 0; nt < 4; nt++) bv[nt] = b_out[bn * 128 + (wn * 4 + nt) * 16 + c16];

  bool ownL = (tg >= 0) && ((tg >> 7) == bn) && (((tg >> 6) & 1) == wn);
  int ntO = (tg >> 4) & 3;
  int tgc = tg & 15;
  const float descale = 1.f / 32.f;     // undo the *32 on W_out fp8

#pragma unroll
  for (int mt = 0; mt < 4; mt++){
#pragma unroll
    for (int r = 0; r < 4; r++){
      int rl = wm * 64 + mt * 16 + quad * 4 + r;  // C/D: col=lane&15, row=quad*4+reg (m89)
      float l[4];
#pragma unroll
      for (int nt = 0; nt < 4; nt++) l[nt] = fmaf(acc[mt][nt][r], descale, bv[nt]);
      if (bn == 0 && wn == 0 && c16 == 0) blank_g[lin0 + rl] = l[0];
      if (ownL && c16 == tgc){
        float v = l[0];
#pragma unroll
        for (int k = 1; k < 4; k++) v = (ntO == k) ? l[k] : v;
        lbl_g[lin0 + rl] = v;
      }
      float s = __expf(l[0]) + __expf(l[1]) + __expf(l[2]) + __expf(l[3]);
      s += __shfl_xor(s, 1, 64);
      s += __shfl_xor(s, 2, 64);
      s += __shfl_xor(s, 4, 64);
      s += __shfl_xor(s, 8, 64);
      if (c16 == 0) redS[wn][rl] = s;
    }
  }
  __syncthreads();
  if (tid < 128)
    atomicAdd(&S[lin0 + tid], redS[0][tid] + redS[1][tid]);
}

// ------------- parallel lse: blankd/lbld = x - log(S), whole machine -------------
__global__ __launch_bounds__(256) void k_lse(
    const float* __restrict__ S, const float* __restrict__ blank_g,
    const float* __restrict__ lbl_g,
    float* __restrict__ blankd, float* __restrict__ lbld)
{
  int cell = blockIdx.x * 256 + threadIdx.x;   // 66560 = 260*256
  float lse = __logf(S[cell]);
  int u = (cell % cTU) >> 8;
  blankd[cell] = blank_g[cell] - lse;
  lbld[cell] = (u < cU) ? (lbl_g[cell] - lse) : NEGF;
}

// ------------- RNN-T alpha DP: SKIP-2 diagonal steps (r15-verified), 2-stream staging -------------
// Final reduce fused: lane 0 atomicAdds -res/4 into out[0] (zeroed by k_pre).
__global__ __launch_bounds__(256) void k_dp(
    const float* __restrict__ blankd, const float* __restrict__ lbld,
    const int* __restrict__ in_len, const int* __restrict__ tgt_len,
    float* __restrict__ out)
{
  __shared__ float sbb[cTU];   // 65 KB, (u,t): index u*256+t
  __shared__ float slb[cTU];   // 65 KB
  __shared__ float sS[256];    // alpha[t][63] history (lane 63)
  int b = blockIdx.x;
  int tl  = tgt_len[b];                // 32..64
  size_t base = (size_t)b * cTU;
  for (int i = threadIdx.x; i < cTU / 4; i += 256){
    ((float4*)sbb)[i] = ((const float4*)(blankd + base))[i];
    float4 v = ((const float4*)(lbld + base))[i];
    int row = (i * 4) >> 8;            // float4 never crosses a 256-elem row
    if (row >= tl){ v.x = NEGF; v.y = NEGF; v.z = NEGF; v.w = NEGF; }
    ((float4*)slb)[i] = v;
  }
  __syncthreads();
  if (threadIdx.x >= 64) return;

  int u = threadIdx.x;                 // 0..63
  int til = in_len[b] - 1;
  bool cap64 = (tl == 64);
  bool isTL = (u == tl);
  const float* pbu  = sbb + (u << 8);
  const float* pbu1 = sbb + (((u >= 1) ? u - 1 : 0) << 8);
  const float* plu1 = slb + (((u >= 1) ? u - 1 : 0) << 8);
  const float* plu2 = slb + (((u >= 2) ? u - 2 : 0) << 8);
  bool u1 = (u >= 1), u2 = (u >= 2);
  float fb = pbu[til];                 // blank at (u, til); used by lane tl only

  float A = (u == 0) ? 0.f : NEGF;     // alpha on even diagonal d = 2g
  float res = 0.f;

  auto ld = [&](const float* p, int i, bool ok) -> float {
    bool v = ok & (i >= 0) & (i <= 255);
    int ic = (i < 0) ? 0 : ((i > 255) ? 255 : i);
    float x = p[ic];
    return v ? x : NEGF;
  };

  int i0 = -u;
  float o0 = ld(pbu,  i0,     true);   // bb[t-2][u]
  float o1 = ld(pbu,  i0 + 1, true);   // bb[t-1][u]
  float o2 = ld(plu1, i0 + 1, u1);     // lb[t-1][u-1]
  float o3 = ld(pbu1, i0 + 1, u1);     // bb[t-1][u-1]
  float o4 = ld(plu1, i0 + 2, u1);     // lb[t][u-1]
  float o5 = ld(plu2, i0 + 2, u2);     // lb[t][u-2]

  for (int g = 0; g < 159; g++){
    float c0 = o0, c1 = o1, c2 = o2, c3 = o3, c4 = o4, c5 = o5;
    int i0n = i0 + 2;
    o0 = ld(pbu,  i0n,     true);
    o1 = ld(pbu,  i0n + 1, true);
    o2 = ld(plu1, i0n + 1, u1);
    o3 = ld(pbu1, i0n + 1, u1);
    o4 = ld(plu1, i0n + 2, u1);
    o5 = ld(plu2, i0n + 2, u2);

    float up1 = __shfl_up(A, 1, 64);
    float up2 = __shfl_up(A, 2, 64);

    float C0 = c0 + c1;
    float C1 = logadd(c2 + c1, c3 + c4);
    float C2 = c5 + c4;

    bool tv1 = (i0 + 1 >= 0) & (i0 + 1 <= 255);
    float Amid = logadd(A + c0, up1 + c2);
    Amid = tv1 ? Amid : NEGF;
    bool tv2 = (i0 + 2 >= 0) & (i0 + 2 <= 255);
    float Anew = logadd(logadd(A + C0, up1 + C1), up2 + C2);
    Anew = tv2 ? Anew : NEGF;

    if (isTL && (i0 + 1) == til) res = Amid + fb;
    if (isTL && (i0 + 2) == til) res = Anew + fb;
    if (u == 63){
      if (tv1) sS[i0 + 1] = Amid;
      if (tv2) sS[i0 + 2] = Anew;
    }
    A = Anew;
    i0 = i0n;
  }

  if (cap64){
    const float* pb64 = sbb + (64 << 8);
    const float* pl63 = slb + (63 << 8);
    float A64 = sS[0] + pl63[0];       // alpha[0][64]
    for (int t = 1; t <= til; t++)
      A64 = logadd(A64 + pb64[t - 1], sS[t] + pl63[t]);
    if (u == 0) res = A64 + pb64[til];
  }

  // butterfly-sum broadcasts the single captured value (others hold 0)
  res += __shfl_xor(res, 1, 64);
  res += __shfl_xor(res, 2, 64);
  res += __shfl_xor(res, 4, 64);
  res += __shfl_xor(res, 8, 64);
  res += __shfl_xor(res, 16, 64);
  res += __shfl_xor(res, 32, 64);
  if (u == 0) atomicAdd(out, -0.25f * res);
}

extern "C" void kernel_launch(void* const* d_in, const int* in_sizes, int n_in,
                              void* d_out, int out_size, void* d_ws, size_t ws_size,
                              hipStream_t stream)
{
  (void)in_sizes; (void)n_in; (void)out_size; (void)ws_size;
  const float* inputs = (const float*)d_in[0];   // (4,256,80)
  const float* W_enc  = (const float*)d_in[1];   // (80,512)
  const float* emb    = (const float*)d_in[2];   // (1024,512)
  const float* W_jenc = (const float*)d_in[3];   // (512,512)
  const float* W_jdec = (const float*)d_in[4];   // (512,512)
  const float* b_j    = (const float*)d_in[5];   // (512)
  const float* W_out  = (const float*)d_in[6];   // (512,1024)
  const float* b_out  = (const float*)d_in[7];   // (1024)
  const int* targets  = (const int*)d_in[8];     // (4,64)
  const int* in_len   = (const int*)d_in[9];     // (4)
  const int* tgt_len  = (const int*)d_in[10];    // (4)

  char* w = (char*)d_ws;
  auto alloc = [&](size_t bytes){ char* p = w; w += (bytes + 255) & ~(size_t)255; return p; };
  float* Wcomb   = (float*)alloc((size_t)80 * 512 * 4);
  float* e       = (float*)alloc((size_t)1024 * 512 * 4);
  float* dmatb   = (float*)alloc((size_t)260 * 512 * 4);
  float* blank_g = (float*)alloc((size_t)cM * 4);
  float* lbl_g   = (float*)alloc((size_t)cM * 4);
  float* S       = (float*)alloc((size_t)cM * 4);
  float* blankd  = (float*)alloc((size_t)cM * 4);
  float* lbld    = (float*)alloc((size_t)cM * 4);
  uchar_t* Hbf8  = (uchar_t*)alloc((size_t)520 * 65536);
  uchar_t* WTf8  = (uchar_t*)alloc((size_t)4 * 131072);

  k_pre<<<267, 256, 0, stream>>>(W_enc, W_jenc, Wcomb, emb, targets, W_jdec, b_j, dmatb,
                                 W_out, WTf8, S, (float*)d_out);
  k_gemm_e<<<dim3(2, 256), 256, 0, stream>>>(inputs, Wcomb, e);
  k_hf<<<520, 256, 0, stream>>>(e, dmatb, Hbf8);
  k_joint<<<4160, 256, 0, stream>>>(Hbf8, WTf8, b_out, targets, S, blank_g, lbl_g);
  k_lse<<<260, 256, 0, stream>>>(S, blank_g, lbl_g, blankd, lbld);
  k_dp<<<4, 256, 0, stream>>>(blankd, lbld, in_len, tgt_len, (float*)d_out);
}

// Round 20
// 243.252 us; speedup vs baseline: 1.9108x; 1.0025x over previous
//
#include <hip/hip_runtime.h>
#include <stdint.h>

#define NEGF (-1e30f)

typedef unsigned short ushort_t;
typedef unsigned char uchar_t;
typedef __attribute__((ext_vector_type(2))) long v2i64;
typedef __attribute__((ext_vector_type(4))) float f32x4;

constexpr int cB = 4, cT = 256, cU = 64, cU1 = 65, cV = 1024, cF = 80, cH = 512, cJ = 512;
constexpr int cM = cB * cT * cU1; // 66560
constexpr int cTU = cT * cU1;     // 16640 (per-batch (u,t) plane: u*256+t)

// Padé(2,2) tanh + clamp: max err ~0.016, far below fp8-e4m3 half-step; no v_exp.
__device__ __forceinline__ float tanh_fast(float x){
  float t = x * x;
  float num = x * (27.f + t);
  float den = fmaf(9.f, t, 27.f);
  float r = num * __builtin_amdgcn_rcpf(den);
  return fminf(1.f, fmaxf(-1.f, r));
}

__device__ __forceinline__ float logadd(float x, float y){
  float m = fmaxf(x, y);
  return m + __logf(1.f + __expf(-fabsf(x - y)));
}

__device__ __forceinline__ int pk8(float a, float b, float c, float d){
  int v = __builtin_amdgcn_cvt_pk_fp8_f32(a, b, 0, false);
  v = __builtin_amdgcn_cvt_pk_fp8_f32(c, d, v, true);
  return v;
}

// ------------- fused prologue: 4 independent jobs in one dispatch -------------
// bid 0..255  : e[4 rows] = (inputs @ W_enc) @ W_jenc, block-local two-stage
//               (reference order; kills the Wcomb intermediate + k_gemm_e launch)
// bid 256..385: dmatb(260,512) = emb[padded] @ W_jdec + b_j
// bid 386..417: WTf8 fp8 fragment-order transpose of 32*W_out (2-ks-packed, K=32)
// bid 418..482: zero S[cM]; bid 418 also zeroes out[0] (k_dp atomic target)
__global__ __launch_bounds__(256) void k_pre(
    const float* __restrict__ inputs,
    const float* __restrict__ W_enc, const float* __restrict__ W_jenc,
    const float* __restrict__ emb, const int* __restrict__ targets,
    const float* __restrict__ W_jdec, const float* __restrict__ b_j,
    float* __restrict__ dmatb, float* __restrict__ e,
    const float* __restrict__ W_out, uchar_t* __restrict__ WTf8,
    float* __restrict__ S, float* __restrict__ out_loss)
{
  __shared__ float sA[4][512];
  __shared__ float sIn[4][80];
  int bid = blockIdx.x;
  int tid = threadIdx.x;

  if (bid < 256){
    // ---- e rows m0..m0+3 ----
    int m0 = bid * 4;
    if (tid < 320) sIn[tid / 80][tid % 80] = inputs[m0 * 80 + tid];
    __syncthreads();
    int c0 = tid, c1 = tid + 256;
    float a00 = 0.f, a01 = 0.f, a10 = 0.f, a11 = 0.f;
    float a20 = 0.f, a21 = 0.f, a30 = 0.f, a31 = 0.f;
#pragma unroll 8
    for (int k = 0; k < 80; k++){
      float w0 = W_enc[(size_t)k * 512 + c0];
      float w1 = W_enc[(size_t)k * 512 + c1];
      a00 = fmaf(sIn[0][k], w0, a00); a01 = fmaf(sIn[0][k], w1, a01);
      a10 = fmaf(sIn[1][k], w0, a10); a11 = fmaf(sIn[1][k], w1, a11);
      a20 = fmaf(sIn[2][k], w0, a20); a21 = fmaf(sIn[2][k], w1, a21);
      a30 = fmaf(sIn[3][k], w0, a30); a31 = fmaf(sIn[3][k], w1, a31);
    }
    sA[0][c0] = a00; sA[0][c1] = a01;
    sA[1][c0] = a10; sA[1][c1] = a11;
    sA[2][c0] = a20; sA[2][c1] = a21;
    sA[3][c0] = a30; sA[3][c1] = a31;
    __syncthreads();
    float b00 = 0.f, b01 = 0.f, b10 = 0.f, b11 = 0.f;
    float b20 = 0.f, b21 = 0.f, b30 = 0.f, b31 = 0.f;
#pragma unroll 8
    for (int k = 0; k < 512; k++){
      float w0 = W_jenc[(size_t)k * 512 + c0];
      float w1 = W_jenc[(size_t)k * 512 + c1];
      b00 = fmaf(sA[0][k], w0, b00); b01 = fmaf(sA[0][k], w1, b01);
      b10 = fmaf(sA[1][k], w0, b10); b11 = fmaf(sA[1][k], w1, b11);
      b20 = fmaf(sA[2][k], w0, b20); b21 = fmaf(sA[2][k], w1, b21);
      b30 = fmaf(sA[3][k], w0, b30); b31 = fmaf(sA[3][k], w1, b31);
    }
    e[(size_t)(m0 + 0) * 512 + c0] = b00; e[(size_t)(m0 + 0) * 512 + c1] = b01;
    e[(size_t)(m0 + 1) * 512 + c0] = b10; e[(size_t)(m0 + 1) * 512 + c1] = b11;
    e[(size_t)(m0 + 2) * 512 + c0] = b20; e[(size_t)(m0 + 2) * 512 + c1] = b21;
    e[(size_t)(m0 + 3) * 512 + c0] = b30; e[(size_t)(m0 + 3) * 512 + c1] = b31;
  } else if (bid < 386){
    // ---- dmatb = emb[padded] @ W_jdec + b_j ----
    int id = bid - 256;                  // 0..129
    int bx = id & 1, by = id >> 1;
    int m0 = by * 4;
    int col = bx * 256 + tid;
    for (int i = tid; i < 4 * 512; i += 256){
      int r = i >> 9, c = i & 511;
      int row = m0 + r;
      int b = row / cU1, u = row % cU1;
      int src = (u == 0) ? 0 : targets[b * cU + (u - 1)];
      sA[r][c] = emb[(size_t)src * cH + c];
    }
    __syncthreads();
    float a0 = 0.f, a1 = 0.f, a2 = 0.f, a3 = 0.f;
#pragma unroll 8
    for (int k = 0; k < 512; k++){
      float bv = W_jdec[(size_t)k * cJ + col];
      a0 = fmaf(sA[0][k], bv, a0);
      a1 = fmaf(sA[1][k], bv, a1);
      a2 = fmaf(sA[2][k], bv, a2);
      a3 = fmaf(sA[3][k], bv, a3);
    }
    float bb = b_j[col];
    dmatb[(size_t)(m0 + 0) * cJ + col] = a0 + bb;
    dmatb[(size_t)(m0 + 1) * cJ + col] = a1 + bb;
    dmatb[(size_t)(m0 + 2) * cJ + col] = a2 + bb;
    dmatb[(size_t)(m0 + 3) * cJ + col] = a3 + bb;
  } else if (bid < 418){
    // ---- WTf8[((bn4*8+ksp)*16 + nt16)*1024 + lane*16] ----
    int id = bid - 386;                  // 0..31
    int bn = id & 3, ksp = id >> 2;      // ksp 0..7
    int lane = tid & 63, nth = tid >> 6;
    int c16 = lane & 15, quad = lane >> 4;
    int jA = ksp * 64 + quad * 8;
#pragma unroll
    for (int i = 0; i < 4; i++){
      int nt16 = nth * 4 + i;
      int n = bn * 256 + nt16 * 16 + c16;
      unsigned int p[4];
#pragma unroll
      for (int h = 0; h < 4; h++){
        int j0 = jA + (h >> 1) * 32 + (h & 1) * 4;
        float w0 = W_out[(size_t)(j0 + 0) * cV + n] * 32.f;
        float w1 = W_out[(size_t)(j0 + 1) * cV + n] * 32.f;
        float w2 = W_out[(size_t)(j0 + 2) * cV + n] * 32.f;
        float w3 = W_out[(size_t)(j0 + 3) * cV + n] * 32.f;
        p[h] = (unsigned)pk8(w0, w1, w2, w3);
      }
      uint4 pack; pack.x = p[0]; pack.y = p[1]; pack.z = p[2]; pack.w = p[3];
      *(uint4*)(WTf8 + (((size_t)(bn * 8 + ksp) * 16 + nt16) * 64 + lane) * 16) = pack;
    }
  } else {
    // ---- zero S: 65 blocks x 256 thr x 4 floats = 66560 ----
    int i = (bid - 418) * 1024 + tid * 4;
    float4 z; z.x = 0.f; z.y = 0.f; z.z = 0.f; z.w = 0.f;
    *(float4*)(S + i) = z;
    if (bid == 418 && tid == 0) out_loss[0] = 0.f;
  }
}

// ------------- H fp8 fragment-order, t-minor, coalesced via LDS bounce -------------
__global__ __launch_bounds__(256) void k_hf(const float* __restrict__ e,
                                            const float* __restrict__ dmatb,
                                            uchar_t* __restrict__ Hbf8){
  __shared__ uchar_t sH[16 * 520];    // 16 rows x 512 B, pad 8 B
  int tid = threadIdx.x;
  int wid = tid >> 6, lane = tid & 63;
  int c16 = lane & 15, quad = lane >> 4;
  int bm = blockIdx.x;
  int bu = bm >> 1, thalf = bm & 1;
  int b = bu / cU1;
  int t0 = thalf * 128;

  float dj[8];
  const float4* dp = (const float4*)(dmatb + (size_t)bu * cJ + lane * 8);
  float4 dA = dp[0], dB = dp[1];
  dj[0] = dA.x; dj[1] = dA.y; dj[2] = dA.z; dj[3] = dA.w;
  dj[4] = dB.x; dj[5] = dB.y; dj[6] = dB.z; dj[7] = dB.w;

  const float* erow0 = e + ((size_t)(b * cT + t0)) * cJ + lane * 8;
  uchar_t* outb = Hbf8 + (size_t)bm * 65536 + lane * 16;

  for (int mg = 0; mg < 8; mg++){
#pragma unroll
    for (int rr = 0; rr < 4; rr++){
      int rloc = wid * 4 + rr;
      const float* ep = erow0 + ((size_t)(mg * 16 + rloc)) * cJ;
      float4 e0 = *(const float4*)ep;
      float4 e1 = *(const float4*)(ep + 4);
      int v0 = pk8(tanh_fast(e0.x + dj[0]), tanh_fast(e0.y + dj[1]),
                   tanh_fast(e0.z + dj[2]), tanh_fast(e0.w + dj[3]));
      int v1 = pk8(tanh_fast(e1.x + dj[4]), tanh_fast(e1.y + dj[5]),
                   tanh_fast(e1.z + dj[6]), tanh_fast(e1.w + dj[7]));
      uint2 pk; pk.x = (unsigned)v0; pk.y = (unsigned)v1;
      *(uint2*)(sH + rloc * 520 + lane * 8) = pk;
    }
    __syncthreads();
#pragma unroll
    for (int q = 0; q < 2; q++){
      int ksp = wid * 2 + q;
      uint2 lo = *(const uint2*)(sH + c16 * 520 + ksp * 64 + quad * 8);
      uint2 hi = *(const uint2*)(sH + c16 * 520 + ksp * 64 + 32 + quad * 8);
      uint4 pack; pack.x = lo.x; pack.y = lo.y; pack.z = hi.x; pack.w = hi.y;
      *(uint4*)(outb + ((size_t)ksp * 8 + mg) * 1024) = pack;
    }
    __syncthreads();
  }
}

// ------------- joint GEMM fp8 K=32: 64x64 wave tile, 3 blocks/CU, atomic-S epilogue -------------
// r18/r19-measured ~62 us. VGPR 60 + 64 AGPR, no spill.
__global__ __launch_bounds__(256, 3) void k_joint(
    const uchar_t* __restrict__ Hbf8, const uchar_t* __restrict__ WTf8,
    const float* __restrict__ b_out, const int* __restrict__ targets,
    float* __restrict__ S,
    float* __restrict__ blank_g, float* __restrict__ lbl_g)
{
  __shared__ float redS[2][128];

  int tid = threadIdx.x;
  int wid = tid >> 6, lane = tid & 63;
  int quad = lane >> 4, c16 = lane & 15;
  int wm = wid & 1, wn = wid >> 1;
  int bid = blockIdx.x;
  int bm = ((bid >> 6) << 3) + (bid & 7);
  int bn = (bid >> 3) & 7;                       // 128-col strip
  int bu = bm >> 1, thalf = bm & 1;
  int b = bu / cU1, u = bu - b * cU1;
  int tg = (u < cU) ? targets[b * cU + u] : -1;
  int lin0 = bu * cT + thalf * 128;              // (b,u,t)-linear base

  f32x4 acc[4][4];
#pragma unroll
  for (int i = 0; i < 4; i++)
#pragma unroll
    for (int j = 0; j < 4; j++)
      acc[i][j] = (f32x4){0.f, 0.f, 0.f, 0.f};

  const uchar_t* aP = Hbf8 + (size_t)bm * 65536 + (wm * 4) * 1024 + lane * 16;
  const uchar_t* bP = WTf8 + (size_t)(bn >> 1) * 131072 + ((bn & 1) * 8 + wn * 4) * 1024 + lane * 16;

#pragma unroll
  for (int ksp = 0; ksp < 8; ksp++){
    v2i64 af[4], bf[4];
#pragma unroll
    for (int mt = 0; mt < 4; mt++)
      af[mt] = *(const v2i64*)(aP + (size_t)ksp * 8192 + mt * 1024);
#pragma unroll
    for (int nt = 0; nt < 4; nt++)
      bf[nt] = *(const v2i64*)(bP + (size_t)ksp * 16384 + nt * 1024);
#pragma unroll
    for (int h = 0; h < 2; h++)
#pragma unroll
      for (int mt = 0; mt < 4; mt++)
#pragma unroll
        for (int nt = 0; nt < 4; nt++)
          acc[mt][nt] = __builtin_amdgcn_mfma_f32_16x16x32_fp8_fp8(af[mt][h], bf[nt][h], acc[mt][nt], 0, 0, 0);
  }

  float bv[4];
#pragma unroll
  for (int nt = 0; nt < 4; nt++) bv[nt] = b_out[bn * 128 + (wn * 4 + nt) * 16 + c16];

  bool ownL = (tg >= 0) && ((tg >> 7) == bn) && (((tg >> 6) & 1) == wn);
  int ntO = (tg >> 4) & 3;
  int tgc = tg & 15;
  const float descale = 1.f / 32.f;     // undo the *32 on W_out fp8

#pragma unroll
  for (int mt = 0; mt < 4; mt++){
#pragma unroll
    for (int r = 0; r < 4; r++){
      int rl = wm * 64 + mt * 16 + quad * 4 + r;  // C/D: col=lane&15, row=quad*4+reg (m89)
      float l[4];
#pragma unroll
      for (int nt = 0; nt < 4; nt++) l[nt] = fmaf(acc[mt][nt][r], descale, bv[nt]);
      if (bn == 0 && wn == 0 && c16 == 0) blank_g[lin0 + rl] = l[0];
      if (ownL && c16 == tgc){
        float v = l[0];
#pragma unroll
        for (int k = 1; k < 4; k++) v = (ntO == k) ? l[k] : v;
        lbl_g[lin0 + rl] = v;
      }
      float s = __expf(l[0]) + __expf(l[1]) + __expf(l[2]) + __expf(l[3]);
      s += __shfl_xor(s, 1, 64);
      s += __shfl_xor(s, 2, 64);
      s += __shfl_xor(s, 4, 64);
      s += __shfl_xor(s, 8, 64);
      if (c16 == 0) redS[wn][rl] = s;
    }
  }
  __syncthreads();
  if (tid < 128)
    atomicAdd(&S[lin0 + tid], redS[0][tid] + redS[1][tid]);
}

// ------------- parallel lse: blankd/lbld = x - log(S), whole machine -------------
__global__ __launch_bounds__(256) void k_lse(
    const float* __restrict__ S, const float* __restrict__ blank_g,
    const float* __restrict__ lbl_g,
    float* __restrict__ blankd, float* __restrict__ lbld)
{
  int cell = blockIdx.x * 256 + threadIdx.x;   // 66560 = 260*256
  float lse = __logf(S[cell]);
  int u = (cell % cTU) >> 8;
  blankd[cell] = blank_g[cell] - lse;
  lbld[cell] = (u < cU) ? (lbl_g[cell] - lse) : NEGF;
}

// ------------- RNN-T alpha DP: SKIP-2 diagonal steps (r15-verified), 2-stream staging -------------
// Final reduce fused: lane 0 atomicAdds -res/4 into out[0] (zeroed by k_pre).
__global__ __launch_bounds__(256) void k_dp(
    const float* __restrict__ blankd, const float* __restrict__ lbld,
    const int* __restrict__ in_len, const int* __restrict__ tgt_len,
    float* __restrict__ out)
{
  __shared__ float sbb[cTU];   // 65 KB, (u,t): index u*256+t
  __shared__ float slb[cTU];   // 65 KB
  __shared__ float sS[256];    // alpha[t][63] history (lane 63)
  int b = blockIdx.x;
  int tl  = tgt_len[b];                // 32..64
  size_t base = (size_t)b * cTU;
  for (int i = threadIdx.x; i < cTU / 4; i += 256){
    ((float4*)sbb)[i] = ((const float4*)(blankd + base))[i];
    float4 v = ((const float4*)(lbld + base))[i];
    int row = (i * 4) >> 8;            // float4 never crosses a 256-elem row
    if (row >= tl){ v.x = NEGF; v.y = NEGF; v.z = NEGF; v.w = NEGF; }
    ((float4*)slb)[i] = v;
  }
  __syncthreads();
  if (threadIdx.x >= 64) return;

  int u = threadIdx.x;                 // 0..63
  int til = in_len[b] - 1;
  bool cap64 = (tl == 64);
  bool isTL = (u == tl);
  const float* pbu  = sbb + (u << 8);
  const float* pbu1 = sbb + (((u >= 1) ? u - 1 : 0) << 8);
  const float* plu1 = slb + (((u >= 1) ? u - 1 : 0) << 8);
  const float* plu2 = slb + (((u >= 2) ? u - 2 : 0) << 8);
  bool u1 = (u >= 1), u2 = (u >= 2);
  float fb = pbu[til];                 // blank at (u, til); used by lane tl only

  float A = (u == 0) ? 0.f : NEGF;     // alpha on even diagonal d = 2g
  float res = 0.f;

  auto ld = [&](const float* p, int i, bool ok) -> float {
    bool v = ok & (i >= 0) & (i <= 255);
    int ic = (i < 0) ? 0 : ((i > 255) ? 255 : i);
    float x = p[ic];
    return v ? x : NEGF;
  };

  int i0 = -u;
  float o0 = ld(pbu,  i0,     true);   // bb[t-2][u]
  float o1 = ld(pbu,  i0 + 1, true);   // bb[t-1][u]
  float o2 = ld(plu1, i0 + 1, u1);     // lb[t-1][u-1]
  float o3 = ld(pbu1, i0 + 1, u1);     // bb[t-1][u-1]
  float o4 = ld(plu1, i0 + 2, u1);     // lb[t][u-1]
  float o5 = ld(plu2, i0 + 2, u2);     // lb[t][u-2]

  for (int g = 0; g < 159; g++){
    float c0 = o0, c1 = o1, c2 = o2, c3 = o3, c4 = o4, c5 = o5;
    int i0n = i0 + 2;
    o0 = ld(pbu,  i0n,     true);
    o1 = ld(pbu,  i0n + 1, true);
    o2 = ld(plu1, i0n + 1, u1);
    o3 = ld(pbu1, i0n + 1, u1);
    o4 = ld(plu1, i0n + 2, u1);
    o5 = ld(plu2, i0n + 2, u2);

    float up1 = __shfl_up(A, 1, 64);
    float up2 = __shfl_up(A, 2, 64);

    float C0 = c0 + c1;
    float C1 = logadd(c2 + c1, c3 + c4);
    float C2 = c5 + c4;

    bool tv1 = (i0 + 1 >= 0) & (i0 + 1 <= 255);
    float Amid = logadd(A + c0, up1 + c2);
    Amid = tv1 ? Amid : NEGF;
    bool tv2 = (i0 + 2 >= 0) & (i0 + 2 <= 255);
    float Anew = logadd(logadd(A + C0, up1 + C1), up2 + C2);
    Anew = tv2 ? Anew : NEGF;

    if (isTL && (i0 + 1) == til) res = Amid + fb;
    if (isTL && (i0 + 2) == til) res = Anew + fb;
    if (u == 63){
      if (tv1) sS[i0 + 1] = Amid;
      if (tv2) sS[i0 + 2] = Anew;
    }
    A = Anew;
    i0 = i0n;
  }

  if (cap64){
    const float* pb64 = sbb + (64 << 8);
    const float* pl63 = slb + (63 << 8);
    float A64 = sS[0] + pl63[0];       // alpha[0][64]
    for (int t = 1; t <= til; t++)
      A64 = logadd(A64 + pb64[t - 1], sS[t] + pl63[t]);
    if (u == 0) res = A64 + pb64[til];
  }

  // butterfly-sum broadcasts the single captured value (others hold 0)
  res += __shfl_xor(res, 1, 64);
  res += __shfl_xor(res, 2, 64);
  res += __shfl_xor(res, 4, 64);
  res += __shfl_xor(res, 8, 64);
  res += __shfl_xor(res, 16, 64);
  res += __shfl_xor(res, 32, 64);
  if (u == 0) atomicAdd(out, -0.25f * res);
}

extern "C" void kernel_launch(void* const* d_in, const int* in_sizes, int n_in,
                              void* d_out, int out_size, void* d_ws, size_t ws_size,
                              hipStream_t stream)
{
  (void)in_sizes; (void)n_in; (void)out_size; (void)ws_size;
  const float* inputs = (const float*)d_in[0];   // (4,256,80)
  const float* W_enc  = (const float*)d_in[1];   // (80,512)
  const float* emb    = (const float*)d_in[2];   // (1024,512)
  const float* W_jenc = (const float*)d_in[3];   // (512,512)
  const float* W_jdec = (const float*)d_in[4];   // (512,512)
  const float* b_j    = (const float*)d_in[5];   // (512)
  const float* W_out  = (const float*)d_in[6];   // (512,1024)
  const float* b_out  = (const float*)d_in[7];   // (1024)
  const int* targets  = (const int*)d_in[8];     // (4,64)
  const int* in_len   = (const int*)d_in[9];     // (4)
  const int* tgt_len  = (const int*)d_in[10];    // (4)

  char* w = (char*)d_ws;
  auto alloc = [&](size_t bytes){ char* p = w; w += (bytes + 255) & ~(size_t)255; return p; };
  float* e       = (float*)alloc((size_t)1024 * 512 * 4);
  float* dmatb   = (float*)alloc((size_t)260 * 512 * 4);
  float* blank_g = (float*)alloc((size_t)cM * 4);
  float* lbl_g   = (float*)alloc((size_t)cM * 4);
  float* S       = (float*)alloc((size_t)cM * 4);
  float* blankd  = (float*)alloc((size_t)cM * 4);
  float* lbld    = (float*)alloc((size_t)cM * 4);
  uchar_t* Hbf8  = (uchar_t*)alloc((size_t)520 * 65536);
  uchar_t* WTf8  = (uchar_t*)alloc((size_t)4 * 131072);

  k_pre<<<483, 256, 0, stream>>>(inputs, W_enc, W_jenc, emb, targets, W_jdec, b_j,
                                 dmatb, e, W_out, WTf8, S, (float*)d_out);
  k_hf<<<520, 256, 0, stream>>>(e, dmatb, Hbf8);
  k_joint<<<4160, 256, 0, stream>>>(Hbf8, WTf8, b_out, targets, S, blank_g, lbl_g);
  k_lse<<<260, 256, 0, stream>>>(S, blank_g, lbl_g, blankd, lbld);
  k_dp<<<4, 256, 0, stream>>>(blankd, lbld, in_len, tgt_len, (float*)d_out);
}

// Round 21
// 243.149 us; speedup vs baseline: 1.9116x; 1.0004x over previous
//
#include <hip/hip_runtime.h>
#include <stdint.h>

#define NEGF (-1e30f)

typedef unsigned short ushort_t;
typedef unsigned char uchar_t;
typedef __attribute__((ext_vector_type(2))) long v2i64;
typedef __attribute__((ext_vector_type(4))) float f32x4;

constexpr int cB = 4, cT = 256, cU = 64, cU1 = 65, cV = 1024, cF = 80, cH = 512, cJ = 512;
constexpr int cM = cB * cT * cU1; // 66560
constexpr int cTU = cT * cU1;     // 16640 (per-batch (u,t) plane: u*256+t)

// Padé(2,2) tanh + clamp: max err ~0.016, far below fp8-e4m3 half-step; no v_exp.
__device__ __forceinline__ float tanh_fast(float x){
  float t = x * x;
  float num = x * (27.f + t);
  float den = fmaf(9.f, t, 27.f);
  float r = num * __builtin_amdgcn_rcpf(den);
  return fminf(1.f, fmaxf(-1.f, r));
}

__device__ __forceinline__ float logadd(float x, float y){
  float m = fmaxf(x, y);
  return m + __logf(1.f + __expf(-fabsf(x - y)));
}

__device__ __forceinline__ int pk8(float a, float b, float c, float d){
  int v = __builtin_amdgcn_cvt_pk_fp8_f32(a, b, 0, false);
  v = __builtin_amdgcn_cvt_pk_fp8_f32(c, d, v, true);
  return v;
}

// ------------- fused prologue: 4 independent jobs in one dispatch -------------
// bid 0..255  : e[4 rows] = (inputs @ W_enc) @ W_jenc, block-local two-stage
// bid 256..385: dmatb(260,512) = emb[padded] @ W_jdec + b_j
// bid 386..417: WTf8 fp8 fragment-order transpose of 32*W_out (2-ks-packed, K=32)
// bid 418..482: zero S[cM]; bid 418 also zeroes out[0] (k_dp atomic target)
__global__ __launch_bounds__(256) void k_pre(
    const float* __restrict__ inputs,
    const float* __restrict__ W_enc, const float* __restrict__ W_jenc,
    const float* __restrict__ emb, const int* __restrict__ targets,
    const float* __restrict__ W_jdec, const float* __restrict__ b_j,
    float* __restrict__ dmatb, float* __restrict__ e,
    const float* __restrict__ W_out, uchar_t* __restrict__ WTf8,
    float* __restrict__ S, float* __restrict__ out_loss)
{
  __shared__ float sA[4][512];
  __shared__ float sIn[4][80];
  int bid = blockIdx.x;
  int tid = threadIdx.x;

  if (bid < 256){
    // ---- e rows m0..m0+3 ----
    int m0 = bid * 4;
    // r20 BUG FIX: 320 elements with 256 threads needs a strided loop (the
    // single `if (tid < 320)` left sIn[3][16..79] uninitialized -> absmax 16).
    for (int i = tid; i < 320; i += 256)
      sIn[i / 80][i % 80] = inputs[m0 * 80 + i];
    __syncthreads();
    int c0 = tid, c1 = tid + 256;
    float a00 = 0.f, a01 = 0.f, a10 = 0.f, a11 = 0.f;
    float a20 = 0.f, a21 = 0.f, a30 = 0.f, a31 = 0.f;
#pragma unroll 8
    for (int k = 0; k < 80; k++){
      float w0 = W_enc[(size_t)k * 512 + c0];
      float w1 = W_enc[(size_t)k * 512 + c1];
      a00 = fmaf(sIn[0][k], w0, a00); a01 = fmaf(sIn[0][k], w1, a01);
      a10 = fmaf(sIn[1][k], w0, a10); a11 = fmaf(sIn[1][k], w1, a11);
      a20 = fmaf(sIn[2][k], w0, a20); a21 = fmaf(sIn[2][k], w1, a21);
      a30 = fmaf(sIn[3][k], w0, a30); a31 = fmaf(sIn[3][k], w1, a31);
    }
    sA[0][c0] = a00; sA[0][c1] = a01;
    sA[1][c0] = a10; sA[1][c1] = a11;
    sA[2][c0] = a20; sA[2][c1] = a21;
    sA[3][c0] = a30; sA[3][c1] = a31;
    __syncthreads();
    float b00 = 0.f, b01 = 0.f, b10 = 0.f, b11 = 0.f;
    float b20 = 0.f, b21 = 0.f, b30 = 0.f, b31 = 0.f;
#pragma unroll 8
    for (int k = 0; k < 512; k++){
      float w0 = W_jenc[(size_t)k * 512 + c0];
      float w1 = W_jenc[(size_t)k * 512 + c1];
      b00 = fmaf(sA[0][k], w0, b00); b01 = fmaf(sA[0][k], w1, b01);
      b10 = fmaf(sA[1][k], w0, b10); b11 = fmaf(sA[1][k], w1, b11);
      b20 = fmaf(sA[2][k], w0, b20); b21 = fmaf(sA[2][k], w1, b21);
      b30 = fmaf(sA[3][k], w0, b30); b31 = fmaf(sA[3][k], w1, b31);
    }
    e[(size_t)(m0 + 0) * 512 + c0] = b00; e[(size_t)(m0 + 0) * 512 + c1] = b01;
    e[(size_t)(m0 + 1) * 512 + c0] = b10; e[(size_t)(m0 + 1) * 512 + c1] = b11;
    e[(size_t)(m0 + 2) * 512 + c0] = b20; e[(size_t)(m0 + 2) * 512 + c1] = b21;
    e[(size_t)(m0 + 3) * 512 + c0] = b30; e[(size_t)(m0 + 3) * 512 + c1] = b31;
  } else if (bid < 386){
    // ---- dmatb = emb[padded] @ W_jdec + b_j ----
    int id = bid - 256;                  // 0..129
    int bx = id & 1, by = id >> 1;
    int m0 = by * 4;
    int col = bx * 256 + tid;
    for (int i = tid; i < 4 * 512; i += 256){
      int r = i >> 9, c = i & 511;
      int row = m0 + r;
      int b = row / cU1, u = row % cU1;
      int src = (u == 0) ? 0 : targets[b * cU + (u - 1)];
      sA[r][c] = emb[(size_t)src * cH + c];
    }
    __syncthreads();
    float a0 = 0.f, a1 = 0.f, a2 = 0.f, a3 = 0.f;
#pragma unroll 8
    for (int k = 0; k < 512; k++){
      float bv = W_jdec[(size_t)k * cJ + col];
      a0 = fmaf(sA[0][k], bv, a0);
      a1 = fmaf(sA[1][k], bv, a1);
      a2 = fmaf(sA[2][k], bv, a2);
      a3 = fmaf(sA[3][k], bv, a3);
    }
    float bb = b_j[col];
    dmatb[(size_t)(m0 + 0) * cJ + col] = a0 + bb;
    dmatb[(size_t)(m0 + 1) * cJ + col] = a1 + bb;
    dmatb[(size_t)(m0 + 2) * cJ + col] = a2 + bb;
    dmatb[(size_t)(m0 + 3) * cJ + col] = a3 + bb;
  } else if (bid < 418){
    // ---- WTf8[((bn4*8+ksp)*16 + nt16)*1024 + lane*16] ----
    int id = bid - 386;                  // 0..31
    int bn = id & 3, ksp = id >> 2;      // ksp 0..7
    int lane = tid & 63, nth = tid >> 6;
    int c16 = lane & 15, quad = lane >> 4;
    int jA = ksp * 64 + quad * 8;
#pragma unroll
    for (int i = 0; i < 4; i++){
      int nt16 = nth * 4 + i;
      int n = bn * 256 + nt16 * 16 + c16;
      unsigned int p[4];
#pragma unroll
      for (int h = 0; h < 4; h++){
        int j0 = jA + (h >> 1) * 32 + (h & 1) * 4;
        float w0 = W_out[(size_t)(j0 + 0) * cV + n] * 32.f;
        float w1 = W_out[(size_t)(j0 + 1) * cV + n] * 32.f;
        float w2 = W_out[(size_t)(j0 + 2) * cV + n] * 32.f;
        float w3 = W_out[(size_t)(j0 + 3) * cV + n] * 32.f;
        p[h] = (unsigned)pk8(w0, w1, w2, w3);
      }
      uint4 pack; pack.x = p[0]; pack.y = p[1]; pack.z = p[2]; pack.w = p[3];
      *(uint4*)(WTf8 + (((size_t)(bn * 8 + ksp) * 16 + nt16) * 64 + lane) * 16) = pack;
    }
  } else {
    // ---- zero S: 65 blocks x 256 thr x 4 floats = 66560 ----
    int i = (bid - 418) * 1024 + tid * 4;
    float4 z; z.x = 0.f; z.y = 0.f; z.z = 0.f; z.w = 0.f;
    *(float4*)(S + i) = z;
    if (bid == 418 && tid == 0) out_loss[0] = 0.f;
  }
}

// ------------- H fp8 fragment-order, t-minor, coalesced via LDS bounce -------------
__global__ __launch_bounds__(256) void k_hf(const float* __restrict__ e,
                                            const float* __restrict__ dmatb,
                                            uchar_t* __restrict__ Hbf8){
  __shared__ uchar_t sH[16 * 520];    // 16 rows x 512 B, pad 8 B
  int tid = threadIdx.x;
  int wid = tid >> 6, lane = tid & 63;
  int c16 = lane & 15, quad = lane >> 4;
  int bm = blockIdx.x;
  int bu = bm >> 1, thalf = bm & 1;
  int b = bu / cU1;
  int t0 = thalf * 128;

  float dj[8];
  const float4* dp = (const float4*)(dmatb + (size_t)bu * cJ + lane * 8);
  float4 dA = dp[0], dB = dp[1];
  dj[0] = dA.x; dj[1] = dA.y; dj[2] = dA.z; dj[3] = dA.w;
  dj[4] = dB.x; dj[5] = dB.y; dj[6] = dB.z; dj[7] = dB.w;

  const float* erow0 = e + ((size_t)(b * cT + t0)) * cJ + lane * 8;
  uchar_t* outb = Hbf8 + (size_t)bm * 65536 + lane * 16;

  for (int mg = 0; mg < 8; mg++){
#pragma unroll
    for (int rr = 0; rr < 4; rr++){
      int rloc = wid * 4 + rr;
      const float* ep = erow0 + ((size_t)(mg * 16 + rloc)) * cJ;
      float4 e0 = *(const float4*)ep;
      float4 e1 = *(const float4*)(ep + 4);
      int v0 = pk8(tanh_fast(e0.x + dj[0]), tanh_fast(e0.y + dj[1]),
                   tanh_fast(e0.z + dj[2]), tanh_fast(e0.w + dj[3]));
      int v1 = pk8(tanh_fast(e1.x + dj[4]), tanh_fast(e1.y + dj[5]),
                   tanh_fast(e1.z + dj[6]), tanh_fast(e1.w + dj[7]));
      uint2 pk; pk.x = (unsigned)v0; pk.y = (unsigned)v1;
      *(uint2*)(sH + rloc * 520 + lane * 8) = pk;
    }
    __syncthreads();
#pragma unroll
    for (int q = 0; q < 2; q++){
      int ksp = wid * 2 + q;
      uint2 lo = *(const uint2*)(sH + c16 * 520 + ksp * 64 + quad * 8);
      uint2 hi = *(const uint2*)(sH + c16 * 520 + ksp * 64 + 32 + quad * 8);
      uint4 pack; pack.x = lo.x; pack.y = lo.y; pack.z = hi.x; pack.w = hi.y;
      *(uint4*)(outb + ((size_t)ksp * 8 + mg) * 1024) = pack;
    }
    __syncthreads();
  }
}

// ------------- joint GEMM fp8 K=32: 64x64 wave tile, 3 blocks/CU, atomic-S epilogue -------------
__global__ __launch_bounds__(256, 3) void k_joint(
    const uchar_t* __restrict__ Hbf8, const uchar_t* __restrict__ WTf8,
    const float* __restrict__ b_out, const int* __restrict__ targets,
    float* __restrict__ S,
    float* __restrict__ blank_g, float* __restrict__ lbl_g)
{
  __shared__ float redS[2][128];

  int tid = threadIdx.x;
  int wid = tid >> 6, lane = tid & 63;
  int quad = lane >> 4, c16 = lane & 15;
  int wm = wid & 1, wn = wid >> 1;
  int bid = blockIdx.x;
  int bm = ((bid >> 6) << 3) + (bid & 7);
  int bn = (bid >> 3) & 7;                       // 128-col strip
  int bu = bm >> 1, thalf = bm & 1;
  int b = bu / cU1, u = bu - b * cU1;
  int tg = (u < cU) ? targets[b * cU + u] : -1;
  int lin0 = bu * cT + thalf * 128;              // (b,u,t)-linear base

  f32x4 acc[4][4];
#pragma unroll
  for (int i = 0; i < 4; i++)
#pragma unroll
    for (int j = 0; j < 4; j++)
      acc[i][j] = (f32x4){0.f, 0.f, 0.f, 0.f};

  const uchar_t* aP = Hbf8 + (size_t)bm * 65536 + (wm * 4) * 1024 + lane * 16;
  const uchar_t* bP = WTf8 + (size_t)(bn >> 1) * 131072 + ((bn & 1) * 8 + wn * 4) * 1024 + lane * 16;

#pragma unroll
  for (int ksp = 0; ksp < 8; ksp++){
    v2i64 af[4], bf[4];
#pragma unroll
    for (int mt = 0; mt < 4; mt++)
      af[mt] = *(const v2i64*)(aP + (size_t)ksp * 8192 + mt * 1024);
#pragma unroll
    for (int nt = 0; nt < 4; nt++)
      bf[nt] = *(const v2i64*)(bP + (size_t)ksp * 16384 + nt * 1024);
#pragma unroll
    for (int h = 0; h < 2; h++)
#pragma unroll
      for (int mt = 0; mt < 4; mt++)
#pragma unroll
        for (int nt = 0; nt < 4; nt++)
          acc[mt][nt] = __builtin_amdgcn_mfma_f32_16x16x32_fp8_fp8(af[mt][h], bf[nt][h], acc[mt][nt], 0, 0, 0);
  }

  float bv[4];
#pragma unroll
  for (int nt = 0; nt < 4; nt++) bv[nt] = b_out[bn * 128 + (wn * 4 + nt) * 16 + c16];

  bool ownL = (tg >= 0) && ((tg >> 7) == bn) && (((tg >> 6) & 1) == wn);
  int ntO = (tg >> 4) & 3;
  int tgc = tg & 15;
  const float descale = 1.f / 32.f;     // undo the *32 on W_out fp8

#pragma unroll
  for (int mt = 0; mt < 4; mt++){
#pragma unroll
    for (int r = 0; r < 4; r++){
      int rl = wm * 64 + mt * 16 + quad * 4 + r;  // C/D: col=lane&15, row=quad*4+reg (m89)
      float l[4];
#pragma unroll
      for (int nt = 0; nt < 4; nt++) l[nt] = fmaf(acc[mt][nt][r], descale, bv[nt]);
      if (bn == 0 && wn == 0 && c16 == 0) blank_g[lin0 + rl] = l[0];
      if (ownL && c16 == tgc){
        float v = l[0];
#pragma unroll
        for (int k = 1; k < 4; k++) v = (ntO == k) ? l[k] : v;
        lbl_g[lin0 + rl] = v;
      }
      float s = __expf(l[0]) + __expf(l[1]) + __expf(l[2]) + __expf(l[3]);
      s += __shfl_xor(s, 1, 64);
      s += __shfl_xor(s, 2, 64);
      s += __shfl_xor(s, 4, 64);
      s += __shfl_xor(s, 8, 64);
      if (c16 == 0) redS[wn][rl] = s;
    }
  }
  __syncthreads();
  if (tid < 128)
    atomicAdd(&S[lin0 + tid], redS[0][tid] + redS[1][tid]);
}

// ------------- parallel lse: blankd/lbld = x - log(S), whole machine -------------
__global__ __launch_bounds__(256) void k_lse(
    const float* __restrict__ S, const float* __restrict__ blank_g,
    const float* __restrict__ lbl_g,
    float* __restrict__ blankd, float* __restrict__ lbld)
{
  int cell = blockIdx.x * 256 + threadIdx.x;   // 66560 = 260*256
  float lse = __logf(S[cell]);
  int u = (cell % cTU) >> 8;
  blankd[cell] = blank_g[cell] - lse;
  lbld[cell] = (u < cU) ? (lbl_g[cell] - lse) : NEGF;
}

// ------------- RNN-T alpha DP: SKIP-2 diagonal steps, 2-stream staging -------------
__global__ __launch_bounds__(256) void k_dp(
    const float* __restrict__ blankd, const float* __restrict__ lbld,
    const int* __restrict__ in_len, const int* __restrict__ tgt_len,
    float* __restrict__ out)
{
  __shared__ float sbb[cTU];   // 65 KB, (u,t): index u*256+t
  __shared__ float slb[cTU];   // 65 KB
  __shared__ float sS[256];    // alpha[t][63] history (lane 63)
  int b = blockIdx.x;
  int tl  = tgt_len[b];                // 32..64
  size_t base = (size_t)b * cTU;
  for (int i = threadIdx.x; i < cTU / 4; i += 256){
    ((float4*)sbb)[i] = ((const float4*)(blankd + base))[i];
    float4 v = ((const float4*)(lbld + base))[i];
    int row = (i * 4) >> 8;            // float4 never crosses a 256-elem row
    if (row >= tl){ v.x = NEGF; v.y = NEGF; v.z = NEGF; v.w = NEGF; }
    ((float4*)slb)[i] = v;
  }
  __syncthreads();
  if (threadIdx.x >= 64) return;

  int u = threadIdx.x;                 // 0..63
  int til = in_len[b] - 1;
  bool cap64 = (tl == 64);
  bool isTL = (u == tl);
  const float* pbu  = sbb + (u << 8);
  const float* pbu1 = sbb + (((u >= 1) ? u - 1 : 0) << 8);
  const float* plu1 = slb + (((u >= 1) ? u - 1 : 0) << 8);
  const float* plu2 = slb + (((u >= 2) ? u - 2 : 0) << 8);
  bool u1 = (u >= 1), u2 = (u >= 2);
  float fb = pbu[til];                 // blank at (u, til); used by lane tl only

  float A = (u == 0) ? 0.f : NEGF;     // alpha on even diagonal d = 2g
  float res = 0.f;

  auto ld = [&](const float* p, int i, bool ok) -> float {
    bool v = ok & (i >= 0) & (i <= 255);
    int ic = (i < 0) ? 0 : ((i > 255) ? 255 : i);
    float x = p[ic];
    return v ? x : NEGF;
  };

  int i0 = -u;
  float o0 = ld(pbu,  i0,     true);   // bb[t-2][u]
  float o1 = ld(pbu,  i0 + 1, true);   // bb[t-1][u]
  float o2 = ld(plu1, i0 + 1, u1);     // lb[t-1][u-1]
  float o3 = ld(pbu1, i0 + 1, u1);     // bb[t-1][u-1]
  float o4 = ld(plu1, i0 + 2, u1);     // lb[t][u-1]
  float o5 = ld(plu2, i0 + 2, u2);     // lb[t][u-2]

  for (int g = 0; g < 159; g++){
    float c0 = o0, c1 = o1, c2 = o2, c3 = o3, c4 = o4, c5 = o5;
    int i0n = i0 + 2;
    o0 = ld(pbu,  i0n,     true);
    o1 = ld(pbu,  i0n + 1, true);
    o2 = ld(plu1, i0n + 1, u1);
    o3 = ld(pbu1, i0n + 1, u1);
    o4 = ld(plu1, i0n + 2, u1);
    o5 = ld(plu2, i0n + 2, u2);

    float up1 = __shfl_up(A, 1, 64);
    float up2 = __shfl_up(A, 2, 64);

    float C0 = c0 + c1;
    float C1 = logadd(c2 + c1, c3 + c4);
    float C2 = c5 + c4;

    bool tv1 = (i0 + 1 >= 0) & (i0 + 1 <= 255);
    float Amid = logadd(A + c0, up1 + c2);
    Amid = tv1 ? Amid : NEGF;
    bool tv2 = (i0 + 2 >= 0) & (i0 + 2 <= 255);
    float Anew = logadd(logadd(A + C0, up1 + C1), up2 + C2);
    Anew = tv2 ? Anew : NEGF;

    if (isTL && (i0 + 1) == til) res = Amid + fb;
    if (isTL && (i0 + 2) == til) res = Anew + fb;
    if (u == 63){
      if (tv1) sS[i0 + 1] = Amid;
      if (tv2) sS[i0 + 2] = Anew;
    }
    A = Anew;
    i0 = i0n;
  }

  if (cap64){
    const float* pb64 = sbb + (64 << 8);
    const float* pl63 = slb + (63 << 8);
    float A64 = sS[0] + pl63[0];       // alpha[0][64]
    for (int t = 1; t <= til; t++)
      A64 = logadd(A64 + pb64[t - 1], sS[t] + pl63[t]);
    if (u == 0) res = A64 + pb64[til];
  }

  // butterfly-sum broadcasts the single captured value (others hold 0)
  res += __shfl_xor(res, 1, 64);
  res += __shfl_xor(res, 2, 64);
  res += __shfl_xor(res, 4, 64);
  res += __shfl_xor(res, 8, 64);
  res += __shfl_xor(res, 16, 64);
  res += __shfl_xor(res, 32, 64);
  if (u == 0) atomicAdd(out, -0.25f * res);
}

extern "C" void kernel_launch(void* const* d_in, const int* in_sizes, int n_in,
                              void* d_out, int out_size, void* d_ws, size_t ws_size,
                              hipStream_t stream)
{
  (void)in_sizes; (void)n_in; (void)out_size; (void)ws_size;
  const float* inputs = (const float*)d_in[0];   // (4,256,80)
  const float* W_enc  = (const float*)d_in[1];   // (80,512)
  const float* emb    = (const float*)d_in[2];   // (1024,512)
  const float* W_jenc = (const float*)d_in[3];   // (512,512)
  const float* W_jdec = (const float*)d_in[4];   // (512,512)
  const float* b_j    = (const float*)d_in[5];   // (512)
  const float* W_out  = (const float*)d_in[6];   // (512,1024)
  const float* b_out  = (const float*)d_in[7];   // (1024)
  const int* targets  = (const int*)d_in[8];     // (4,64)
  const int* in_len   = (const int*)d_in[9];     // (4)
  const int* tgt_len  = (const int*)d_in[10];    // (4)

  char* w = (char*)d_ws;
  auto alloc = [&](size_t bytes){ char* p = w; w += (bytes + 255) & ~(size_t)255; return p; };
  float* e       = (float*)alloc((size_t)1024 * 512 * 4);
  float* dmatb   = (float*)alloc((size_t)260 * 512 * 4);
  float* blank_g = (float*)alloc((size_t)cM * 4);
  float* lbl_g   = (float*)alloc((size_t)cM * 4);
  float* S       = (float*)alloc((size_t)cM * 4);
  float* blankd  = (float*)alloc((size_t)cM * 4);
  float* lbld    = (float*)alloc((size_t)cM * 4);
  uchar_t* Hbf8  = (uchar_t*)alloc((size_t)520 * 65536);
  uchar_t* WTf8  = (uchar_t*)alloc((size_t)4 * 131072);

  k_pre<<<483, 256, 0, stream>>>(inputs, W_enc, W_jenc, emb, targets, W_jdec, b_j,
                                 dmatb, e, W_out, WTf8, S, (float*)d_out);
  k_hf<<<520, 256, 0, stream>>>(e, dmatb, Hbf8);
  k_joint<<<4160, 256, 0, stream>>>(Hbf8, WTf8, b_out, targets, S, blank_g, lbl_g);
  k_lse<<<260, 256, 0, stream>>>(S, blank_g, lbl_g, blankd, lbld);
  k_dp<<<4, 256, 0, stream>>>(blankd, lbld, in_len, tgt_len, (float*)d_out);
}